// Round 1
// baseline (1898.986 us; speedup 1.0000x reference)
//
#include <hip/hip_runtime.h>
#include <hip/hip_bf16.h>

#define DD 1024
#define HH 4096
#define EE 8
#define NN 4096   // B*T tokens

typedef __attribute__((ext_vector_type(8))) short bf16x8;
typedef __attribute__((ext_vector_type(4))) float f32x4;

// global_load_lds needs addrspace-qualified pointers; cast via integer.
// (generic global addr == as(1) numerically; generic LDS low 32 bits == as(3) offset)
#define AS1P(p) ((__attribute__((address_space(1))) void*)(unsigned long long)(const void*)(p))
#define AS3P(p) ((__attribute__((address_space(3))) void*)(unsigned int)(unsigned long long)(const void*)(p))

__device__ inline f32x4 mfma16(bf16x8 a, bf16x8 b, f32x4 c) {
    return __builtin_amdgcn_mfma_f32_16x16x32_bf16(a, b, c, 0, 0, 0);
}

// ---------------------------------------------------------------------------
// Transpose + fp32->bf16 convert: dst[e][c][r] = src[e][r][c] * (SCALE? g[e][r] : 1)
// If SCALE: badd[e][c] += sum_r bvec[e][r]*src[e][r][c]   (eb @ W folded bias)
// ---------------------------------------------------------------------------
template <bool SCALE>
__global__ __launch_bounds__(256) void transpose_conv(
    const float* __restrict__ src, __hip_bfloat16* __restrict__ dst,
    const float* __restrict__ g, const float* __restrict__ bvec,
    float* __restrict__ badd, int R, int C)
{
    __shared__ float tile[32][33];
    const int e  = blockIdx.z;
    const int r0 = blockIdx.y * 32;
    const int c0 = blockIdx.x * 32;
    const float* s = src + (size_t)e * R * C;
    const int t  = threadIdx.x;
    const int tr = t / 32, tc = t % 32;

    #pragma unroll
    for (int i = 0; i < 4; i++)
        tile[tr + i * 8][tc] = s[(size_t)(r0 + tr + i * 8) * C + c0 + tc];
    __syncthreads();

    __hip_bfloat16* d = dst + (size_t)e * R * C;
    #pragma unroll
    for (int i = 0; i < 4; i++) {
        const int c = c0 + tr + i * 8;   // dst row
        const int r = r0 + tc;           // dst col
        float v = tile[tc][tr + i * 8];
        if (SCALE) v *= g[e * R + r];
        d[(size_t)c * R + r] = __float2bfloat16(v);
    }
    if (SCALE) {
        if (t < 32) {
            float ssum = 0.f;
            #pragma unroll
            for (int rr = 0; rr < 32; rr++)
                ssum += bvec[e * R + r0 + rr] * tile[rr][t];
            atomicAdd(&badd[e * C + c0 + t], ssum);
        }
    }
}

// ---------------------------------------------------------------------------
// Per-token: LN1 -> router logits -> top2+softmax -> scatter; store LN2-normalized
// token (WITHOUT eg/eb — folded into weights) as bf16.
// ---------------------------------------------------------------------------
__global__ __launch_bounds__(256) void token_kernel(
    const float* __restrict__ x, const float* __restrict__ lng, const float* __restrict__ lnb,
    const float* __restrict__ rw, __hip_bfloat16* __restrict__ xhat,
    int* __restrict__ counts, int* __restrict__ lists, float* __restrict__ gates)
{
    const int i = blockIdx.x;
    const int t = threadIdx.x;
    __shared__ float sA[256], sB[256];
    __shared__ float slog[32];

    float4 xv = ((const float4*)(x + (size_t)i * DD))[t];
    float s1 = xv.x + xv.y + xv.z + xv.w;
    float s2 = xv.x * xv.x + xv.y * xv.y + xv.z * xv.z + xv.w * xv.w;
    sA[t] = s1; sB[t] = s2;
    __syncthreads();
    for (int s = 128; s > 0; s >>= 1) {
        if (t < s) { sA[t] += sA[t + s]; sB[t] += sB[t + s]; }
        __syncthreads();
    }
    const float mu  = sA[0] * (1.0f / DD);
    const float var = sB[0] * (1.0f / DD) - mu * mu;
    const float rstd = rsqrtf(var + 1e-5f);
    __syncthreads();

    float4 gv = ((const float4*)lng)[t];
    float4 bv = ((const float4*)lnb)[t];
    float xf[4];
    xf[0] = (xv.x - mu) * rstd * gv.x + bv.x;
    xf[1] = (xv.y - mu) * rstd * gv.y + bv.y;
    xf[2] = (xv.z - mu) * rstd * gv.z + bv.z;
    xf[3] = (xv.w - mu) * rstd * gv.w + bv.w;

    // router logits partials
    float lp[8];
    #pragma unroll
    for (int e = 0; e < 8; e++) lp[e] = 0.f;
    {
        const float4* r4 = (const float4*)(rw + (size_t)(t * 4) * EE);
        #pragma unroll
        for (int j = 0; j < 4; j++) {
            float4 ra = r4[j * 2], rb = r4[j * 2 + 1];
            lp[0] += xf[j] * ra.x; lp[1] += xf[j] * ra.y;
            lp[2] += xf[j] * ra.z; lp[3] += xf[j] * ra.w;
            lp[4] += xf[j] * rb.x; lp[5] += xf[j] * rb.y;
            lp[6] += xf[j] * rb.z; lp[7] += xf[j] * rb.w;
        }
    }
    const int lane = t & 63, wid = t >> 6;
    #pragma unroll
    for (int e = 0; e < 8; e++) {
        float v = lp[e];
        #pragma unroll
        for (int o = 32; o > 0; o >>= 1) v += __shfl_down(v, o, 64);
        if (lane == 0) slog[e * 4 + wid] = v;
    }

    // LN2 (normalize xf; eg/eb folded into weights)
    s1 = xf[0] + xf[1] + xf[2] + xf[3];
    s2 = xf[0] * xf[0] + xf[1] * xf[1] + xf[2] * xf[2] + xf[3] * xf[3];
    sA[t] = s1; sB[t] = s2;
    __syncthreads();
    for (int s = 128; s > 0; s >>= 1) {
        if (t < s) { sA[t] += sA[t + s]; sB[t] += sB[t + s]; }
        __syncthreads();
    }
    const float mu2  = sA[0] * (1.0f / DD);
    const float var2 = sB[0] * (1.0f / DD) - mu2 * mu2;
    const float rstd2 = rsqrtf(var2 + 1e-5f);

    union { ushort4 v; __hip_bfloat16 h[4]; } u;
    u.h[0] = __float2bfloat16((xf[0] - mu2) * rstd2);
    u.h[1] = __float2bfloat16((xf[1] - mu2) * rstd2);
    u.h[2] = __float2bfloat16((xf[2] - mu2) * rstd2);
    u.h[3] = __float2bfloat16((xf[3] - mu2) * rstd2);
    ((ushort4*)(xhat + (size_t)i * DD))[t] = u.v;

    if (t == 0) {
        float lg[8];
        #pragma unroll
        for (int e = 0; e < 8; e++)
            lg[e] = slog[e * 4] + slog[e * 4 + 1] + slog[e * 4 + 2] + slog[e * 4 + 3];
        int i0 = 0;
        #pragma unroll
        for (int e = 1; e < 8; e++) if (lg[e] > lg[i0]) i0 = e;
        int i1 = (i0 == 0) ? 1 : 0;
        #pragma unroll
        for (int e = 0; e < 8; e++) { if (e != i0 && lg[e] > lg[i1]) i1 = e; }
        const float ex = __expf(lg[i1] - lg[i0]);   // <= 1
        const float g0 = 1.f / (1.f + ex);
        const float g1 = ex / (1.f + ex);
        int p0 = atomicAdd(&counts[i0], 1);
        lists[i0 * NN + p0] = i; gates[i0 * NN + p0] = g0;
        int p1 = atomicAdd(&counts[i1], 1);
        lists[i1 * NN + p1] = i; gates[i1 * NN + p1] = g1;
    }
}

// ---------------------------------------------------------------------------
// GEMM1: hid[pair,h] = clip( (A@W1'+b1') * silu(clip(A@W2'+b2', +-20)), +-1e4 )
// A rows gathered from xhat by token list; 128x128 tile, BK=32, 4 waves.
// ---------------------------------------------------------------------------
__global__ __launch_bounds__(256) void gemm1_kernel(
    const __hip_bfloat16* __restrict__ xhat,
    const __hip_bfloat16* __restrict__ w1t, const __hip_bfloat16* __restrict__ w2t,
    const float* __restrict__ b1, const float* __restrict__ b2,
    const float* __restrict__ b1a, const float* __restrict__ b2a,
    const int* __restrict__ counts, const int* __restrict__ lists,
    __hip_bfloat16* __restrict__ hid)
{
    const int e = blockIdx.z;
    const int cnt = counts[e];
    const int m0 = blockIdx.x * 128;
    if (m0 >= cnt) return;
    int base = 0;
    #pragma unroll
    for (int j = 0; j < 8; j++) base += (j < e) ? counts[j] : 0;
    const int h0 = blockIdx.y * 128;

    __shared__ __align__(16) __hip_bfloat16 As[128 * 32];
    __shared__ __align__(16) __hip_bfloat16 B1s[128 * 32];
    __shared__ __align__(16) __hip_bfloat16 B2s[128 * 32];
    __shared__ int toks[128];

    const int t = threadIdx.x;
    const int lane = t & 63;
    const int w = t >> 6;
    const int wr = w >> 1, wc = w & 1;
    const int rsel = lane & 15;
    const int ksel = (lane >> 4) * 8;

    if (t < 128) toks[t] = lists[e * NN + min(m0 + t, cnt - 1)];

    f32x4 acc1[16], acc2[16];
    const f32x4 z4 = {0.f, 0.f, 0.f, 0.f};
    #pragma unroll
    for (int q = 0; q < 16; q++) { acc1[q] = z4; acc2[q] = z4; }

    const __hip_bfloat16* w1e = w1t + (size_t)e * HH * DD + (size_t)h0 * DD;
    const __hip_bfloat16* w2e = w2t + (size_t)e * HH * DD + (size_t)h0 * DD;

    const int flatA = w * 64 + lane;
    const int flatB = (4 + w) * 64 + lane;
    const int rowA = flatA >> 2, kgA = (flatA & 3) * 8;
    const int rowB = flatB >> 2, kgB = (flatB & 3) * 8;

    __syncthreads();   // toks visible

    const __hip_bfloat16* gA0 = xhat + (size_t)toks[rowA] * DD + kgA;
    const __hip_bfloat16* gA1 = xhat + (size_t)toks[rowB] * DD + kgB;
    const __hip_bfloat16* g10 = w1e + (size_t)rowA * DD + kgA;
    const __hip_bfloat16* g11 = w1e + (size_t)rowB * DD + kgB;
    const __hip_bfloat16* g20 = w2e + (size_t)rowA * DD + kgA;
    const __hip_bfloat16* g21 = w2e + (size_t)rowB * DD + kgB;
    __hip_bfloat16* lA0 = As  + w * 512;
    __hip_bfloat16* lA1 = As  + (4 + w) * 512;
    __hip_bfloat16* l10 = B1s + w * 512;
    __hip_bfloat16* l11 = B1s + (4 + w) * 512;
    __hip_bfloat16* l20 = B2s + w * 512;
    __hip_bfloat16* l21 = B2s + (4 + w) * 512;

    for (int k0 = 0; k0 < DD; k0 += 32) {
        __builtin_amdgcn_global_load_lds(AS1P(gA0 + k0), AS3P(lA0), 16, 0, 0);
        __builtin_amdgcn_global_load_lds(AS1P(gA1 + k0), AS3P(lA1), 16, 0, 0);
        __builtin_amdgcn_global_load_lds(AS1P(g10 + k0), AS3P(l10), 16, 0, 0);
        __builtin_amdgcn_global_load_lds(AS1P(g11 + k0), AS3P(l11), 16, 0, 0);
        __builtin_amdgcn_global_load_lds(AS1P(g20 + k0), AS3P(l20), 16, 0, 0);
        __builtin_amdgcn_global_load_lds(AS1P(g21 + k0), AS3P(l21), 16, 0, 0);
        __syncthreads();   // drains vmcnt before barrier

        bf16x8 af[4], bf1[4], bf2[4];
        #pragma unroll
        for (int m = 0; m < 4; m++)
            af[m] = *(const bf16x8*)&As[(wr * 64 + m * 16 + rsel) * 32 + ksel];
        #pragma unroll
        for (int n = 0; n < 4; n++) {
            bf1[n] = *(const bf16x8*)&B1s[(wc * 64 + n * 16 + rsel) * 32 + ksel];
            bf2[n] = *(const bf16x8*)&B2s[(wc * 64 + n * 16 + rsel) * 32 + ksel];
        }
        #pragma unroll
        for (int m = 0; m < 4; m++)
            #pragma unroll
            for (int n = 0; n < 4; n++) {
                acc1[m * 4 + n] = mfma16(af[m], bf1[n], acc1[m * 4 + n]);
                acc2[m * 4 + n] = mfma16(af[m], bf2[n], acc2[m * 4 + n]);
            }
        __syncthreads();   // reads done before restage
    }

    const int rq = (lane >> 4) * 4;
    const int cq = lane & 15;
    #pragma unroll
    for (int mi = 0; mi < 4; mi++) {
        #pragma unroll
        for (int ni = 0; ni < 4; ni++) {
            f32x4 v1 = acc1[mi * 4 + ni];
            f32x4 v2 = acc2[mi * 4 + ni];
            const int hcol = h0 + wc * 64 + ni * 16 + cq;
            const float bb1 = b1[e * HH + hcol] + b1a[e * HH + hcol];
            const float bb2 = b2[e * HH + hcol] + b2a[e * HH + hcol];
            #pragma unroll
            for (int r = 0; r < 4; r++) {
                const int pos = m0 + wr * 64 + mi * 16 + rq + r;
                if (pos < cnt) {
                    float x1 = v1[r] + bb1;
                    float x2 = v2[r] + bb2;
                    x2 = fminf(fmaxf(x2, -20.f), 20.f);
                    float hv = x1 * (x2 / (1.f + __expf(-x2)));
                    hv = fminf(fmaxf(hv, -1e4f), 1e4f);
                    hid[(size_t)(base + pos) * HH + hcol] = __float2bfloat16(hv);
                }
            }
        }
    }
}

// ---------------------------------------------------------------------------
// GEMM2: out[token,d] += gate * clip(hid@Wo + bo, +-1e4)
// ---------------------------------------------------------------------------
__global__ __launch_bounds__(256) void gemm2_kernel(
    const __hip_bfloat16* __restrict__ hid, const __hip_bfloat16* __restrict__ wot,
    const float* __restrict__ bo, const int* __restrict__ counts,
    const int* __restrict__ lists, const float* __restrict__ gates,
    float* __restrict__ out)
{
    const int e = blockIdx.z;
    const int cnt = counts[e];
    const int m0 = blockIdx.x * 128;
    if (m0 >= cnt) return;
    int base = 0;
    #pragma unroll
    for (int j = 0; j < 8; j++) base += (j < e) ? counts[j] : 0;
    const int d0 = blockIdx.y * 128;

    __shared__ __align__(16) __hip_bfloat16 As[128 * 32];
    __shared__ __align__(16) __hip_bfloat16 Bs[128 * 32];

    const int t = threadIdx.x;
    const int lane = t & 63;
    const int w = t >> 6;
    const int wr = w >> 1, wc = w & 1;
    const int rsel = lane & 15;
    const int ksel = (lane >> 4) * 8;

    f32x4 acc[16];
    const f32x4 z4 = {0.f, 0.f, 0.f, 0.f};
    #pragma unroll
    for (int q = 0; q < 16; q++) acc[q] = z4;

    const __hip_bfloat16* we = wot + ((size_t)e * DD + d0) * HH;

    const int flatA = w * 64 + lane;
    const int flatB = (4 + w) * 64 + lane;
    const int rowA = flatA >> 2, kgA = (flatA & 3) * 8;
    const int rowB = flatB >> 2, kgB = (flatB & 3) * 8;
    const int arowA = base + min(m0 + rowA, cnt - 1);
    const int arowB = base + min(m0 + rowB, cnt - 1);

    const __hip_bfloat16* gA0 = hid + (size_t)arowA * HH + kgA;
    const __hip_bfloat16* gA1 = hid + (size_t)arowB * HH + kgB;
    const __hip_bfloat16* gB0 = we + (size_t)rowA * HH + kgA;
    const __hip_bfloat16* gB1 = we + (size_t)rowB * HH + kgB;
    __hip_bfloat16* lA0 = As + w * 512;
    __hip_bfloat16* lA1 = As + (4 + w) * 512;
    __hip_bfloat16* lB0 = Bs + w * 512;
    __hip_bfloat16* lB1 = Bs + (4 + w) * 512;

    for (int k0 = 0; k0 < HH; k0 += 32) {
        __builtin_amdgcn_global_load_lds(AS1P(gA0 + k0), AS3P(lA0), 16, 0, 0);
        __builtin_amdgcn_global_load_lds(AS1P(gA1 + k0), AS3P(lA1), 16, 0, 0);
        __builtin_amdgcn_global_load_lds(AS1P(gB0 + k0), AS3P(lB0), 16, 0, 0);
        __builtin_amdgcn_global_load_lds(AS1P(gB1 + k0), AS3P(lB1), 16, 0, 0);
        __syncthreads();

        bf16x8 af[4], bfr[4];
        #pragma unroll
        for (int m = 0; m < 4; m++)
            af[m] = *(const bf16x8*)&As[(wr * 64 + m * 16 + rsel) * 32 + ksel];
        #pragma unroll
        for (int n = 0; n < 4; n++)
            bfr[n] = *(const bf16x8*)&Bs[(wc * 64 + n * 16 + rsel) * 32 + ksel];
        #pragma unroll
        for (int m = 0; m < 4; m++)
            #pragma unroll
            for (int n = 0; n < 4; n++)
                acc[m * 4 + n] = mfma16(af[m], bfr[n], acc[m * 4 + n]);
        __syncthreads();
    }

    const int rq = (lane >> 4) * 4;
    const int cq = lane & 15;
    #pragma unroll
    for (int mi = 0; mi < 4; mi++) {
        #pragma unroll
        for (int ni = 0; ni < 4; ni++) {
            const int dcol = d0 + wc * 64 + ni * 16 + cq;
            const float bov = bo[e * DD + dcol];
            #pragma unroll
            for (int r = 0; r < 4; r++) {
                const int pos = m0 + wr * 64 + mi * 16 + rq + r;
                if (pos < cnt) {
                    const int tok = lists[e * NN + pos];
                    const float gt = gates[e * NN + pos];
                    float v = acc[mi * 4 + ni][r] + bov;
                    v = fminf(fmaxf(v, -1e4f), 1e4f);
                    atomicAdd(out + (size_t)tok * DD + dcol, v * gt);
                }
            }
        }
    }
}

// ---------------------------------------------------------------------------
extern "C" void kernel_launch(void* const* d_in, const int* in_sizes, int n_in,
                              void* d_out, int out_size, void* d_ws, size_t ws_size,
                              hipStream_t stream)
{
    const float* x   = (const float*)d_in[0];
    const float* lng = (const float*)d_in[1];
    const float* lnb = (const float*)d_in[2];
    const float* rw  = (const float*)d_in[3];
    const float* eg  = (const float*)d_in[4];
    const float* eb  = (const float*)d_in[5];
    const float* W1  = (const float*)d_in[6];
    const float* b1  = (const float*)d_in[7];
    const float* W2  = (const float*)d_in[8];
    const float* b2  = (const float*)d_in[9];
    const float* Wo  = (const float*)d_in[10];
    const float* bo  = (const float*)d_in[11];
    float* out = (float*)d_out;

    char* ws = (char*)d_ws;
    const size_t WSZ = (size_t)EE * HH * DD * 2;      // 64MB per weight matrix
    __hip_bfloat16* W1T  = (__hip_bfloat16*)(ws);
    __hip_bfloat16* W2T  = (__hip_bfloat16*)(ws + WSZ);
    __hip_bfloat16* WoT  = (__hip_bfloat16*)(ws + 2 * WSZ);
    __hip_bfloat16* xhat = (__hip_bfloat16*)(ws + 3 * WSZ);
    __hip_bfloat16* hid  = (__hip_bfloat16*)(ws + 3 * WSZ + (size_t)NN * DD * 2);
    char* small = ws + 3 * WSZ + (size_t)NN * DD * 2 + (size_t)2 * NN * HH * 2;
    int*   counts = (int*)small;
    float* b1a    = (float*)(small + 256);
    float* b2a    = (float*)(small + 256 + 131072);
    int*   lists  = (int*)(small + 256 + 2 * 131072);
    float* gates  = (float*)(small + 256 + 3 * 131072);

    hipMemsetAsync(d_out, 0, (size_t)out_size * sizeof(float), stream);
    hipMemsetAsync(small, 0, 256 + 2 * 131072, stream);   // counts + b1a + b2a

    // weight prep: W1/W2 scaled by eg, eb@W accumulated into b1a/b2a; Wo plain
    transpose_conv<true ><<<dim3(HH / 32, DD / 32, EE), 256, 0, stream>>>(W1, W1T, eg, eb, b1a, DD, HH);
    transpose_conv<true ><<<dim3(HH / 32, DD / 32, EE), 256, 0, stream>>>(W2, W2T, eg, eb, b2a, DD, HH);
    transpose_conv<false><<<dim3(DD / 32, HH / 32, EE), 256, 0, stream>>>(Wo, WoT, nullptr, nullptr, nullptr, HH, DD);

    token_kernel<<<NN, 256, 0, stream>>>(x, lng, lnb, rw, xhat, counts, lists, gates);

    gemm1_kernel<<<dim3(NN / 128, HH / 128, EE), 256, 0, stream>>>(
        xhat, W1T, W2T, b1, b2, b1a, b2a, counts, lists, hid);
    gemm2_kernel<<<dim3(NN / 128, DD / 128, EE), 256, 0, stream>>>(
        hid, WoT, bo, counts, lists, gates, out);
}

// Round 2
// 800.301 us; speedup vs baseline: 2.3728x; 2.3728x over previous
//
#include <hip/hip_runtime.h>
#include <hip/hip_bf16.h>

#define DD 1024
#define HH 4096
#define EE 8
#define NN 4096   // B*T tokens

typedef __attribute__((ext_vector_type(8))) short bf16x8;
typedef __attribute__((ext_vector_type(4))) float f32x4;

#define AS1P(p) ((__attribute__((address_space(1))) void*)(unsigned long long)(const void*)(p))
#define AS3P(p) ((__attribute__((address_space(3))) void*)(unsigned int)(unsigned long long)(const void*)(p))

__device__ inline f32x4 mfma16(bf16x8 a, bf16x8 b, f32x4 c) {
    return __builtin_amdgcn_mfma_f32_16x16x32_bf16(a, b, c, 0, 0, 0);
}

// ---------------------------------------------------------------------------
// Transpose + fp32->bf16 convert: dst[e][c][r] = src[e][r][c] * (SCALE? g[e][r] : 1)
// If SCALE: badd[e][c] += sum_r bvec[e][r]*src[e][r][c]   (eb @ W folded bias)
// ---------------------------------------------------------------------------
template <bool SCALE>
__global__ __launch_bounds__(256) void transpose_conv(
    const float* __restrict__ src, __hip_bfloat16* __restrict__ dst,
    const float* __restrict__ g, const float* __restrict__ bvec,
    float* __restrict__ badd, int R, int C)
{
    __shared__ float tile[32][33];
    const int e  = blockIdx.z;
    const int r0 = blockIdx.y * 32;
    const int c0 = blockIdx.x * 32;
    const float* s = src + (size_t)e * R * C;
    const int t  = threadIdx.x;
    const int tr = t / 32, tc = t % 32;

    #pragma unroll
    for (int i = 0; i < 4; i++)
        tile[tr + i * 8][tc] = s[(size_t)(r0 + tr + i * 8) * C + c0 + tc];
    __syncthreads();

    __hip_bfloat16* d = dst + (size_t)e * R * C;
    #pragma unroll
    for (int i = 0; i < 4; i++) {
        const int c = c0 + tr + i * 8;   // dst row
        const int r = r0 + tc;           // dst col
        float v = tile[tc][tr + i * 8];
        if (SCALE) v *= g[e * R + r];
        d[(size_t)c * R + r] = __float2bfloat16(v);
    }
    if (SCALE) {
        if (t < 32) {
            float ssum = 0.f;
            #pragma unroll
            for (int rr = 0; rr < 32; rr++)
                ssum += bvec[e * R + r0 + rr] * tile[rr][t];
            atomicAdd(&badd[e * C + c0 + t], ssum);
        }
    }
}

// ---------------------------------------------------------------------------
// Per-token: LN1 -> router -> top2+softmax -> scatter; store LN2-normalized
// token (eg/eb folded into weights) as bf16. Also records each token's two
// (expert,slot) ids for the combine kernel.
// ---------------------------------------------------------------------------
__global__ __launch_bounds__(256) void token_kernel(
    const float* __restrict__ x, const float* __restrict__ lng, const float* __restrict__ lnb,
    const float* __restrict__ rw, __hip_bfloat16* __restrict__ xhat,
    int* __restrict__ counts, int* __restrict__ lists, float* __restrict__ gates,
    int* __restrict__ pairIdx)
{
    const int i = blockIdx.x;
    const int t = threadIdx.x;
    __shared__ float sA[256], sB[256];
    __shared__ float slog[32];

    float4 xv = ((const float4*)(x + (size_t)i * DD))[t];
    float s1 = xv.x + xv.y + xv.z + xv.w;
    float s2 = xv.x * xv.x + xv.y * xv.y + xv.z * xv.z + xv.w * xv.w;
    sA[t] = s1; sB[t] = s2;
    __syncthreads();
    for (int s = 128; s > 0; s >>= 1) {
        if (t < s) { sA[t] += sA[t + s]; sB[t] += sB[t + s]; }
        __syncthreads();
    }
    const float mu  = sA[0] * (1.0f / DD);
    const float var = sB[0] * (1.0f / DD) - mu * mu;
    const float rstd = rsqrtf(var + 1e-5f);
    __syncthreads();

    float4 gv = ((const float4*)lng)[t];
    float4 bv = ((const float4*)lnb)[t];
    float xf[4];
    xf[0] = (xv.x - mu) * rstd * gv.x + bv.x;
    xf[1] = (xv.y - mu) * rstd * gv.y + bv.y;
    xf[2] = (xv.z - mu) * rstd * gv.z + bv.z;
    xf[3] = (xv.w - mu) * rstd * gv.w + bv.w;

    float lp[8];
    #pragma unroll
    for (int e = 0; e < 8; e++) lp[e] = 0.f;
    {
        const float4* r4 = (const float4*)(rw + (size_t)(t * 4) * EE);
        #pragma unroll
        for (int j = 0; j < 4; j++) {
            float4 ra = r4[j * 2], rb = r4[j * 2 + 1];
            lp[0] += xf[j] * ra.x; lp[1] += xf[j] * ra.y;
            lp[2] += xf[j] * ra.z; lp[3] += xf[j] * ra.w;
            lp[4] += xf[j] * rb.x; lp[5] += xf[j] * rb.y;
            lp[6] += xf[j] * rb.z; lp[7] += xf[j] * rb.w;
        }
    }
    const int lane = t & 63, wid = t >> 6;
    #pragma unroll
    for (int e = 0; e < 8; e++) {
        float v = lp[e];
        #pragma unroll
        for (int o = 32; o > 0; o >>= 1) v += __shfl_down(v, o, 64);
        if (lane == 0) slog[e * 4 + wid] = v;
    }

    s1 = xf[0] + xf[1] + xf[2] + xf[3];
    s2 = xf[0] * xf[0] + xf[1] * xf[1] + xf[2] * xf[2] + xf[3] * xf[3];
    sA[t] = s1; sB[t] = s2;
    __syncthreads();
    for (int s = 128; s > 0; s >>= 1) {
        if (t < s) { sA[t] += sA[t + s]; sB[t] += sB[t + s]; }
        __syncthreads();
    }
    const float mu2  = sA[0] * (1.0f / DD);
    const float var2 = sB[0] * (1.0f / DD) - mu2 * mu2;
    const float rstd2 = rsqrtf(var2 + 1e-5f);

    union { ushort4 v; __hip_bfloat16 h[4]; } u;
    u.h[0] = __float2bfloat16((xf[0] - mu2) * rstd2);
    u.h[1] = __float2bfloat16((xf[1] - mu2) * rstd2);
    u.h[2] = __float2bfloat16((xf[2] - mu2) * rstd2);
    u.h[3] = __float2bfloat16((xf[3] - mu2) * rstd2);
    ((ushort4*)(xhat + (size_t)i * DD))[t] = u.v;

    if (t == 0) {
        float lg[8];
        #pragma unroll
        for (int e = 0; e < 8; e++)
            lg[e] = slog[e * 4] + slog[e * 4 + 1] + slog[e * 4 + 2] + slog[e * 4 + 3];
        int i0 = 0;
        #pragma unroll
        for (int e = 1; e < 8; e++) if (lg[e] > lg[i0]) i0 = e;
        int i1 = (i0 == 0) ? 1 : 0;
        #pragma unroll
        for (int e = 0; e < 8; e++) { if (e != i0 && lg[e] > lg[i1]) i1 = e; }
        const float ex = __expf(lg[i1] - lg[i0]);   // <= 1
        const float g0 = 1.f / (1.f + ex);
        const float g1 = ex / (1.f + ex);
        int p0 = atomicAdd(&counts[i0], 1);
        lists[i0 * NN + p0] = i; gates[i0 * NN + p0] = g0;
        int p1 = atomicAdd(&counts[i1], 1);
        lists[i1 * NN + p1] = i; gates[i1 * NN + p1] = g1;
        pairIdx[2 * i]     = i0 * NN + p0;
        pairIdx[2 * i + 1] = i1 * NN + p1;
    }
}

// ---------------------------------------------------------------------------
// GEMM1: hid[pair,h] = clip( (A@W1'+b1') * silu(clip(A@W2'+b2', +-20)), +-1e4 )
// 1D grid, XCD-bijective panel mapping: gid%8 = XCD; all 32 m-blocks of a
// weight panel (h-tile, expert) run on the SAME XCD -> weights cross HBM once.
// BK=64 (128B/row/step) + XOR chunk swizzle (inverse on global src, fwd on read).
// ---------------------------------------------------------------------------
__global__ __launch_bounds__(256) void gemm1_kernel(
    const __hip_bfloat16* __restrict__ xhat,
    const __hip_bfloat16* __restrict__ w1t, const __hip_bfloat16* __restrict__ w2t,
    const float* __restrict__ b1, const float* __restrict__ b2,
    const float* __restrict__ b1a, const float* __restrict__ b2a,
    const int* __restrict__ counts, const int* __restrict__ lists,
    __hip_bfloat16* __restrict__ hid)
{
    const int gid = blockIdx.x;           // 0..8191
    const int xcd = gid & 7;
    const int kk_ = gid >> 3;             // 0..1023
    const int p   = xcd + 8 * (kk_ >> 5); // panel 0..255 (== xcd mod 8)
    const int m   = kk_ & 31;
    const int e   = p >> 5;
    const int h0  = (p & 31) * 128;
    const int cnt = counts[e];
    const int m0  = m * 128;
    if (m0 >= cnt) return;
    int base = 0;
    #pragma unroll
    for (int j = 0; j < 8; j++) base += (j < e) ? counts[j] : 0;

    __shared__ __align__(16) __hip_bfloat16 As [128 * 64];
    __shared__ __align__(16) __hip_bfloat16 B1s[128 * 64];
    __shared__ __align__(16) __hip_bfloat16 B2s[128 * 64];
    __shared__ int toks[128];

    const int t = threadIdx.x;
    const int lane = t & 63;
    const int w = t >> 6;
    const int wr = w >> 1, wc = w & 1;
    const int rsel = lane & 15;

    if (t < 128) toks[t] = lists[e * NN + min(m0 + t, cnt - 1)];

    f32x4 acc1[16], acc2[16];
    const f32x4 z4 = {0.f, 0.f, 0.f, 0.f};
    #pragma unroll
    for (int q = 0; q < 16; q++) { acc1[q] = z4; acc2[q] = z4; }

    const __hip_bfloat16* w1e = w1t + (size_t)e * HH * DD + (size_t)h0 * DD;
    const __hip_bfloat16* w2e = w2t + (size_t)e * HH * DD + (size_t)h0 * DD;

    // staging geometry: wave w stages rows 32w..32w+31; instr i covers 8 rows;
    // lane: row = w*32 + i*8 + (lane>>3), chunk c = lane&7, src chunk = c ^ (row&7)
    const int l3 = lane >> 3;              // == row & 7
    const int cs = (lane & 7) ^ l3;        // inverse-swizzled source chunk

    __syncthreads();   // toks visible

    const __hip_bfloat16* pA[4], *pB1[4], *pB2[4];
    #pragma unroll
    for (int i = 0; i < 4; i++) {
        const int row = w * 32 + i * 8 + l3;
        pA[i]  = xhat + (size_t)toks[row] * DD + cs * 8;
        pB1[i] = w1e + (size_t)row * DD + cs * 8;
        pB2[i] = w2e + (size_t)row * DD + cs * 8;
    }

    for (int k0 = 0; k0 < DD; k0 += 64) {
        #pragma unroll
        for (int i = 0; i < 4; i++) {
            __builtin_amdgcn_global_load_lds(AS1P(pA[i]  + k0), AS3P(As  + w * 2048 + i * 512), 16, 0, 0);
            __builtin_amdgcn_global_load_lds(AS1P(pB1[i] + k0), AS3P(B1s + w * 2048 + i * 512), 16, 0, 0);
            __builtin_amdgcn_global_load_lds(AS1P(pB2[i] + k0), AS3P(B2s + w * 2048 + i * 512), 16, 0, 0);
        }
        __syncthreads();

        #pragma unroll
        for (int kk = 0; kk < 2; kk++) {
            const int gch = kk * 4 + (lane >> 4);
            bf16x8 af[4], bf1[4], bf2[4];
            #pragma unroll
            for (int mi = 0; mi < 4; mi++) {
                const int row = wr * 64 + mi * 16 + rsel;
                const int cr = gch ^ (row & 7);
                af[mi] = *(const bf16x8*)&As[row * 64 + cr * 8];
            }
            #pragma unroll
            for (int n = 0; n < 4; n++) {
                const int row = wc * 64 + n * 16 + rsel;
                const int cr = gch ^ (row & 7);
                bf1[n] = *(const bf16x8*)&B1s[row * 64 + cr * 8];
                bf2[n] = *(const bf16x8*)&B2s[row * 64 + cr * 8];
            }
            #pragma unroll
            for (int mi = 0; mi < 4; mi++)
                #pragma unroll
                for (int n = 0; n < 4; n++) {
                    acc1[mi * 4 + n] = mfma16(af[mi], bf1[n], acc1[mi * 4 + n]);
                    acc2[mi * 4 + n] = mfma16(af[mi], bf2[n], acc2[mi * 4 + n]);
                }
        }
        __syncthreads();
    }

    const int rq = (lane >> 4) * 4;
    const int cq = lane & 15;
    #pragma unroll
    for (int mi = 0; mi < 4; mi++) {
        #pragma unroll
        for (int ni = 0; ni < 4; ni++) {
            f32x4 v1 = acc1[mi * 4 + ni];
            f32x4 v2 = acc2[mi * 4 + ni];
            const int hcol = h0 + wc * 64 + ni * 16 + cq;
            const float bb1 = b1[e * HH + hcol] + b1a[e * HH + hcol];
            const float bb2 = b2[e * HH + hcol] + b2a[e * HH + hcol];
            #pragma unroll
            for (int r = 0; r < 4; r++) {
                const int pos = m0 + wr * 64 + mi * 16 + rq + r;
                if (pos < cnt) {
                    float x1 = v1[r] + bb1;
                    float x2 = v2[r] + bb2;
                    x2 = fminf(fmaxf(x2, -20.f), 20.f);
                    float hv = x1 * (x2 / (1.f + __expf(-x2)));
                    hv = fminf(fmaxf(hv, -1e4f), 1e4f);
                    hid[(size_t)(base + pos) * HH + hcol] = __float2bfloat16(hv);
                }
            }
        }
    }
}

// ---------------------------------------------------------------------------
// GEMM2: pairOut[pair,d] = gate * clip(hid@Wo + bo, +-1e4)   (no atomics)
// Same XCD-bijective mapping: 64 panels (d-tile, expert).
// ---------------------------------------------------------------------------
__global__ __launch_bounds__(256) void gemm2_kernel(
    const __hip_bfloat16* __restrict__ hid, const __hip_bfloat16* __restrict__ wot,
    const float* __restrict__ bo, const int* __restrict__ counts,
    const float* __restrict__ gates_lin, float* __restrict__ pairOut)
{
    const int gid = blockIdx.x;           // 0..2047
    const int xcd = gid & 7;
    const int kk_ = gid >> 3;             // 0..255
    const int p   = xcd + 8 * (kk_ >> 5); // panel 0..63
    const int m   = kk_ & 31;
    const int e   = p >> 3;
    const int d0  = (p & 7) * 128;
    const int cnt = counts[e];
    const int m0  = m * 128;
    if (m0 >= cnt) return;
    int base = 0;
    #pragma unroll
    for (int j = 0; j < 8; j++) base += (j < e) ? counts[j] : 0;

    __shared__ __align__(16) __hip_bfloat16 As[128 * 64];
    __shared__ __align__(16) __hip_bfloat16 Bs[128 * 64];

    const int t = threadIdx.x;
    const int lane = t & 63;
    const int w = t >> 6;
    const int wr = w >> 1, wc = w & 1;
    const int rsel = lane & 15;

    f32x4 acc[16];
    const f32x4 z4 = {0.f, 0.f, 0.f, 0.f};
    #pragma unroll
    for (int q = 0; q < 16; q++) acc[q] = z4;

    const __hip_bfloat16* we = wot + ((size_t)e * DD + d0) * HH;

    const int l3 = lane >> 3;
    const int cs = (lane & 7) ^ l3;

    const __hip_bfloat16* pA[4], *pB[4];
    #pragma unroll
    for (int i = 0; i < 4; i++) {
        const int row = w * 32 + i * 8 + l3;
        const int arow = base + min(m0 + row, cnt - 1);
        pA[i] = hid + (size_t)arow * HH + cs * 8;
        pB[i] = we + (size_t)row * HH + cs * 8;
    }

    for (int k0 = 0; k0 < HH; k0 += 64) {
        #pragma unroll
        for (int i = 0; i < 4; i++) {
            __builtin_amdgcn_global_load_lds(AS1P(pA[i] + k0), AS3P(As + w * 2048 + i * 512), 16, 0, 0);
            __builtin_amdgcn_global_load_lds(AS1P(pB[i] + k0), AS3P(Bs + w * 2048 + i * 512), 16, 0, 0);
        }
        __syncthreads();

        #pragma unroll
        for (int kk = 0; kk < 2; kk++) {
            const int gch = kk * 4 + (lane >> 4);
            bf16x8 af[4], bfr[4];
            #pragma unroll
            for (int mi = 0; mi < 4; mi++) {
                const int row = wr * 64 + mi * 16 + rsel;
                const int cr = gch ^ (row & 7);
                af[mi] = *(const bf16x8*)&As[row * 64 + cr * 8];
            }
            #pragma unroll
            for (int n = 0; n < 4; n++) {
                const int row = wc * 64 + n * 16 + rsel;
                const int cr = gch ^ (row & 7);
                bfr[n] = *(const bf16x8*)&Bs[row * 64 + cr * 8];
            }
            #pragma unroll
            for (int mi = 0; mi < 4; mi++)
                #pragma unroll
                for (int n = 0; n < 4; n++)
                    acc[mi * 4 + n] = mfma16(af[mi], bfr[n], acc[mi * 4 + n]);
        }
        __syncthreads();
    }

    const int rq = (lane >> 4) * 4;
    const int cq = lane & 15;
    #pragma unroll
    for (int mi = 0; mi < 4; mi++) {
        #pragma unroll
        for (int ni = 0; ni < 4; ni++) {
            const int dcol = d0 + wc * 64 + ni * 16 + cq;
            const float bov = bo[e * DD + dcol];
            #pragma unroll
            for (int r = 0; r < 4; r++) {
                const int pos = m0 + wr * 64 + mi * 16 + rq + r;
                if (pos < cnt) {
                    const float gt = gates_lin[e * NN + pos];
                    float v = acc[mi * 4 + ni][r] + bov;
                    v = fminf(fmaxf(v, -1e4f), 1e4f);
                    pairOut[(size_t)(base + pos) * DD + dcol] = v * gt;
                }
            }
        }
    }
}

// ---------------------------------------------------------------------------
// Combine: out[token] = pairOut[slot0] + pairOut[slot1]
// ---------------------------------------------------------------------------
__global__ __launch_bounds__(256) void combine_kernel(
    const float* __restrict__ pairOut, const int* __restrict__ counts,
    const int* __restrict__ pairIdx, float* __restrict__ out)
{
    const int i = blockIdx.x;
    const int t = threadIdx.x;
    const int s0 = pairIdx[2 * i], s1 = pairIdx[2 * i + 1];
    const int e0 = s0 >> 12, p0 = s0 & (NN - 1);
    const int e1 = s1 >> 12, p1 = s1 & (NN - 1);
    int b0 = 0, b1 = 0;
    #pragma unroll
    for (int j = 0; j < 8; j++) {
        const int c = counts[j];
        b0 += (j < e0) ? c : 0;
        b1 += (j < e1) ? c : 0;
    }
    const float4 a = ((const float4*)(pairOut + (size_t)(b0 + p0) * DD))[t];
    const float4 b = ((const float4*)(pairOut + (size_t)(b1 + p1) * DD))[t];
    float4 r; r.x = a.x + b.x; r.y = a.y + b.y; r.z = a.z + b.z; r.w = a.w + b.w;
    ((float4*)(out + (size_t)i * DD))[t] = r;
}

// ---------------------------------------------------------------------------
extern "C" void kernel_launch(void* const* d_in, const int* in_sizes, int n_in,
                              void* d_out, int out_size, void* d_ws, size_t ws_size,
                              hipStream_t stream)
{
    const float* x   = (const float*)d_in[0];
    const float* lng = (const float*)d_in[1];
    const float* lnb = (const float*)d_in[2];
    const float* rw  = (const float*)d_in[3];
    const float* eg  = (const float*)d_in[4];
    const float* eb  = (const float*)d_in[5];
    const float* W1  = (const float*)d_in[6];
    const float* b1  = (const float*)d_in[7];
    const float* W2  = (const float*)d_in[8];
    const float* b2  = (const float*)d_in[9];
    const float* Wo  = (const float*)d_in[10];
    const float* bo  = (const float*)d_in[11];
    float* out = (float*)d_out;

    char* ws = (char*)d_ws;
    const size_t WSZ = (size_t)EE * HH * DD * 2;      // 64MB per weight matrix
    __hip_bfloat16* W1T  = (__hip_bfloat16*)(ws);
    __hip_bfloat16* W2T  = (__hip_bfloat16*)(ws + WSZ);
    __hip_bfloat16* WoT  = (__hip_bfloat16*)(ws + 2 * WSZ);
    __hip_bfloat16* xhat = (__hip_bfloat16*)(ws + 3 * WSZ);
    __hip_bfloat16* hid  = (__hip_bfloat16*)(ws + 3 * WSZ + (size_t)NN * DD * 2);
    char* small = ws + 3 * WSZ + (size_t)NN * DD * 2 + (size_t)2 * NN * HH * 2;
    int*   counts  = (int*)small;
    float* b1a     = (float*)(small + 256);
    float* b2a     = (float*)(small + 256 + 131072);
    int*   lists   = (int*)(small + 256 + 2 * 131072);
    float* gates   = (float*)(small + 256 + 3 * 131072);
    int*   pairIdx = (int*)(small + 256 + 4 * 131072);
    // pairOut (8192 x 1024 f32 = 32MB) aliases W1T: gemm2/combine run after
    // gemm1 is done with W1T; transposes rewrite W1T at the start of every call.
    float* pairOut = (float*)(ws);

    hipMemsetAsync(small, 0, 256 + 2 * 131072, stream);   // counts + b1a + b2a

    transpose_conv<true ><<<dim3(HH / 32, DD / 32, EE), 256, 0, stream>>>(W1, W1T, eg, eb, b1a, DD, HH);
    transpose_conv<true ><<<dim3(HH / 32, DD / 32, EE), 256, 0, stream>>>(W2, W2T, eg, eb, b2a, DD, HH);
    transpose_conv<false><<<dim3(DD / 32, HH / 32, EE), 256, 0, stream>>>(Wo, WoT, nullptr, nullptr, nullptr, HH, DD);

    token_kernel<<<NN, 256, 0, stream>>>(x, lng, lnb, rw, xhat, counts, lists, gates, pairIdx);

    gemm1_kernel<<<8192, 256, 0, stream>>>(
        xhat, W1T, W2T, b1, b2, b1a, b2a, counts, lists, hid);
    gemm2_kernel<<<2048, 256, 0, stream>>>(
        hid, WoT, bo, counts, gates, pairOut);
    combine_kernel<<<NN, 256, 0, stream>>>(pairOut, counts, pairIdx, out);
}

// Round 3
// 579.373 us; speedup vs baseline: 3.2777x; 1.3813x over previous
//
#include <hip/hip_runtime.h>
#include <hip/hip_bf16.h>

#define DD 1024
#define HH 4096
#define EE 8
#define NN 4096   // B*T tokens

typedef __attribute__((ext_vector_type(8))) short bf16x8;
typedef __attribute__((ext_vector_type(4))) float f32x4;
typedef __attribute__((ext_vector_type(8))) unsigned short u16x8;

#define AS1P(p) ((__attribute__((address_space(1))) void*)(unsigned long long)(const void*)(p))
#define AS3P(p) ((__attribute__((address_space(3))) void*)(unsigned int)(unsigned long long)(const void*)(p))

__device__ inline f32x4 mfma16(bf16x8 a, bf16x8 b, f32x4 c) {
    return __builtin_amdgcn_mfma_f32_16x16x32_bf16(a, b, c, 0, 0, 0);
}

// ---------------------------------------------------------------------------
// Transpose + fp32->bf16: dst[e][c][r] = src[e][r][c] * (SCALE? g[e][r] : 1)
// If SCALE: badd[e][c] += sum_r bvec[e][r]*src[e][r][c]   (eb @ W folded bias)
// 64x64 tile, float4 loads, 16B stores.
// ---------------------------------------------------------------------------
template <bool SCALE>
__global__ __launch_bounds__(256) void transpose_conv(
    const float* __restrict__ src, __hip_bfloat16* __restrict__ dst,
    const float* __restrict__ g, const float* __restrict__ bvec,
    float* __restrict__ badd, int R, int C)
{
    __shared__ float tile[64][65];
    __shared__ float sg[64], sb[64];
    const int e  = blockIdx.z;
    const int r0 = blockIdx.y * 64;
    const int c0 = blockIdx.x * 64;
    const int t  = threadIdx.x;
    const float* s = src + (size_t)e * R * C + (size_t)r0 * C + c0;

    if (SCALE && t < 64) {
        sg[t] = g[e * R + r0 + t];
        sb[t] = bvec[e * R + r0 + t];
    }
    #pragma unroll
    for (int i = 0; i < 4; i++) {
        const int rr = i * 16 + (t >> 4);
        const int cc = (t & 15) * 4;
        const float4 v = *(const float4*)(s + (size_t)rr * C + cc);
        tile[rr][cc] = v.x; tile[rr][cc + 1] = v.y;
        tile[rr][cc + 2] = v.z; tile[rr][cc + 3] = v.w;
    }
    __syncthreads();

    __hip_bfloat16* d = dst + (size_t)e * R * C + (size_t)c0 * R + r0;
    #pragma unroll
    for (int i = 0; i < 2; i++) {
        const int id = t + 256 * i;
        const int cc = id >> 3;          // dst-row (src col) 0..63
        const int rb = (id & 7) * 8;     // dst-col (src row) block
        union { u16x8 v; __hip_bfloat16 h[8]; } u;
        #pragma unroll
        for (int j = 0; j < 8; j++) {
            float v = tile[rb + j][cc];
            if (SCALE) v *= sg[rb + j];
            u.h[j] = __float2bfloat16(v);
        }
        *(u16x8*)(d + (size_t)cc * R + rb) = u.v;
    }
    if (SCALE && t < 64) {
        float sum = 0.f;
        #pragma unroll
        for (int rr = 0; rr < 64; rr++) sum += sb[rr] * tile[rr][t];
        atomicAdd(&badd[e * C + c0 + t], sum);
    }
}

// ---------------------------------------------------------------------------
// Per-token: LN1 -> router -> top2+softmax -> scatter; store LN2-normalized
// token (eg/eb folded into weights) as bf16; record (expert,slot) per token.
// ---------------------------------------------------------------------------
__global__ __launch_bounds__(256) void token_kernel(
    const float* __restrict__ x, const float* __restrict__ lng, const float* __restrict__ lnb,
    const float* __restrict__ rw, __hip_bfloat16* __restrict__ xhat,
    int* __restrict__ counts, int* __restrict__ lists, float* __restrict__ gates,
    int* __restrict__ pairIdx)
{
    const int i = blockIdx.x;
    const int t = threadIdx.x;
    __shared__ float sA[256], sB[256];
    __shared__ float slog[32];

    float4 xv = ((const float4*)(x + (size_t)i * DD))[t];
    float s1 = xv.x + xv.y + xv.z + xv.w;
    float s2 = xv.x * xv.x + xv.y * xv.y + xv.z * xv.z + xv.w * xv.w;
    sA[t] = s1; sB[t] = s2;
    __syncthreads();
    for (int s = 128; s > 0; s >>= 1) {
        if (t < s) { sA[t] += sA[t + s]; sB[t] += sB[t + s]; }
        __syncthreads();
    }
    const float mu  = sA[0] * (1.0f / DD);
    const float var = sB[0] * (1.0f / DD) - mu * mu;
    const float rstd = rsqrtf(var + 1e-5f);
    __syncthreads();

    float4 gv = ((const float4*)lng)[t];
    float4 bv = ((const float4*)lnb)[t];
    float xf[4];
    xf[0] = (xv.x - mu) * rstd * gv.x + bv.x;
    xf[1] = (xv.y - mu) * rstd * gv.y + bv.y;
    xf[2] = (xv.z - mu) * rstd * gv.z + bv.z;
    xf[3] = (xv.w - mu) * rstd * gv.w + bv.w;

    float lp[8];
    #pragma unroll
    for (int e = 0; e < 8; e++) lp[e] = 0.f;
    {
        const float4* r4 = (const float4*)(rw + (size_t)(t * 4) * EE);
        #pragma unroll
        for (int j = 0; j < 4; j++) {
            float4 ra = r4[j * 2], rb = r4[j * 2 + 1];
            lp[0] += xf[j] * ra.x; lp[1] += xf[j] * ra.y;
            lp[2] += xf[j] * ra.z; lp[3] += xf[j] * ra.w;
            lp[4] += xf[j] * rb.x; lp[5] += xf[j] * rb.y;
            lp[6] += xf[j] * rb.z; lp[7] += xf[j] * rb.w;
        }
    }
    const int lane = t & 63, wid = t >> 6;
    #pragma unroll
    for (int e = 0; e < 8; e++) {
        float v = lp[e];
        #pragma unroll
        for (int o = 32; o > 0; o >>= 1) v += __shfl_down(v, o, 64);
        if (lane == 0) slog[e * 4 + wid] = v;
    }

    s1 = xf[0] + xf[1] + xf[2] + xf[3];
    s2 = xf[0] * xf[0] + xf[1] * xf[1] + xf[2] * xf[2] + xf[3] * xf[3];
    sA[t] = s1; sB[t] = s2;
    __syncthreads();
    for (int s = 128; s > 0; s >>= 1) {
        if (t < s) { sA[t] += sA[t + s]; sB[t] += sB[t + s]; }
        __syncthreads();
    }
    const float mu2  = sA[0] * (1.0f / DD);
    const float var2 = sB[0] * (1.0f / DD) - mu2 * mu2;
    const float rstd2 = rsqrtf(var2 + 1e-5f);

    union { ushort4 v; __hip_bfloat16 h[4]; } u;
    u.h[0] = __float2bfloat16((xf[0] - mu2) * rstd2);
    u.h[1] = __float2bfloat16((xf[1] - mu2) * rstd2);
    u.h[2] = __float2bfloat16((xf[2] - mu2) * rstd2);
    u.h[3] = __float2bfloat16((xf[3] - mu2) * rstd2);
    ((ushort4*)(xhat + (size_t)i * DD))[t] = u.v;

    if (t == 0) {
        float lg[8];
        #pragma unroll
        for (int e = 0; e < 8; e++)
            lg[e] = slog[e * 4] + slog[e * 4 + 1] + slog[e * 4 + 2] + slog[e * 4 + 3];
        int i0 = 0;
        #pragma unroll
        for (int e = 1; e < 8; e++) if (lg[e] > lg[i0]) i0 = e;
        int i1 = (i0 == 0) ? 1 : 0;
        #pragma unroll
        for (int e = 0; e < 8; e++) { if (e != i0 && lg[e] > lg[i1]) i1 = e; }
        const float ex = __expf(lg[i1] - lg[i0]);   // <= 1
        const float g0 = 1.f / (1.f + ex);
        const float g1 = ex / (1.f + ex);
        int p0 = atomicAdd(&counts[i0], 1);
        lists[i0 * NN + p0] = i; gates[i0 * NN + p0] = g0;
        int p1 = atomicAdd(&counts[i1], 1);
        lists[i1 * NN + p1] = i; gates[i1 * NN + p1] = g1;
        pairIdx[2 * i]     = i0 * NN + p0;
        pairIdx[2 * i + 1] = i1 * NN + p1;
    }
}

// ---------------------------------------------------------------------------
// GEMM1: hid = clip( (A@W1'+b1') * silu(clip(A@W2'+b2', +-20)), +-1e4 )
// BM=256, BN=128, BK=64, 8 waves, double-buffered 2-phase, XCD-bijective grid.
// ---------------------------------------------------------------------------
__global__ __launch_bounds__(512, 2) void gemm1_kernel(
    const __hip_bfloat16* __restrict__ xhat,
    const __hip_bfloat16* __restrict__ w1t, const __hip_bfloat16* __restrict__ w2t,
    const float* __restrict__ b1, const float* __restrict__ b2,
    const float* __restrict__ b1a, const float* __restrict__ b2a,
    const int* __restrict__ counts, const int* __restrict__ lists,
    __hip_bfloat16* __restrict__ hid)
{
    const int gid  = blockIdx.x;          // 0..4095
    const int xcd  = gid & 7;
    const int rest = gid >> 3;            // 0..511
    const int m    = rest & 15;
    const int pidx = rest >> 4;           // 0..31
    const int panel = xcd + 8 * pidx;     // 0..255, all m-blocks of panel on 1 XCD
    const int e   = panel >> 5;
    const int h0  = (panel & 31) * 128;
    const int cnt = counts[e];
    const int m0  = m * 256;
    if (m0 >= cnt) return;
    int base = 0;
    #pragma unroll
    for (int j = 0; j < 8; j++) base += (j < e) ? counts[j] : 0;

    __shared__ __align__(16) __hip_bfloat16 As [2][256 * 64];
    __shared__ __align__(16) __hip_bfloat16 B1s[2][128 * 64];
    __shared__ __align__(16) __hip_bfloat16 B2s[2][128 * 64];
    __shared__ int toks[256];

    const int t = threadIdx.x;
    const int lane = t & 63;
    const int w = t >> 6;                 // 0..7
    const int wr = w >> 1, wc = w & 1;    // 4x2 wave grid, each 64x64/matrix
    const int rsel = lane & 15;

    if (t < 256) toks[t] = lists[e * NN + min(m0 + t, cnt - 1)];

    f32x4 acc1[16], acc2[16];
    const f32x4 z4 = {0.f, 0.f, 0.f, 0.f};
    #pragma unroll
    for (int q = 0; q < 16; q++) { acc1[q] = z4; acc2[q] = z4; }

    const __hip_bfloat16* w1e = w1t + (size_t)e * HH * DD + (size_t)h0 * DD;
    const __hip_bfloat16* w2e = w2t + (size_t)e * HH * DD + (size_t)h0 * DD;

    // staging: row pitch 128B = 8 chunks of 16B; lane covers (row=lane>>3, chunk=lane&7)
    const int l3 = lane >> 3;
    const int cs = (lane & 7) ^ l3;       // inverse-swizzled source chunk

    __syncthreads();   // toks visible

    const __hip_bfloat16 *pA[4], *pB1[2], *pB2[2];
    #pragma unroll
    for (int i = 0; i < 4; i++) {
        const int row = i * 64 + w * 8 + l3;
        pA[i] = xhat + (size_t)toks[row] * DD + cs * 8;
    }
    #pragma unroll
    for (int i = 0; i < 2; i++) {
        const int row = i * 64 + w * 8 + l3;
        pB1[i] = w1e + (size_t)row * DD + cs * 8;
        pB2[i] = w2e + (size_t)row * DD + cs * 8;
    }

    auto STAGE = [&](int buf, int k0) {
        #pragma unroll
        for (int i = 0; i < 4; i++)
            __builtin_amdgcn_global_load_lds(AS1P(pA[i] + k0), AS3P(&As[buf][i * 4096 + w * 512]), 16, 0, 0);
        #pragma unroll
        for (int i = 0; i < 2; i++) {
            __builtin_amdgcn_global_load_lds(AS1P(pB1[i] + k0), AS3P(&B1s[buf][i * 4096 + w * 512]), 16, 0, 0);
            __builtin_amdgcn_global_load_lds(AS1P(pB2[i] + k0), AS3P(&B2s[buf][i * 4096 + w * 512]), 16, 0, 0);
        }
    };
    auto COMPUTE = [&](int buf) {
        #pragma unroll
        for (int kk = 0; kk < 2; kk++) {
            const int gch = kk * 4 + (lane >> 4);
            bf16x8 af[4], bq1[4], bq2[4];
            #pragma unroll
            for (int mi = 0; mi < 4; mi++) {
                const int row = wr * 64 + mi * 16 + rsel;
                af[mi] = *(const bf16x8*)&As[buf][row * 64 + (gch ^ (row & 7)) * 8];
            }
            #pragma unroll
            for (int n = 0; n < 4; n++) {
                const int row = wc * 64 + n * 16 + rsel;
                const int cr = gch ^ (row & 7);
                bq1[n] = *(const bf16x8*)&B1s[buf][row * 64 + cr * 8];
                bq2[n] = *(const bf16x8*)&B2s[buf][row * 64 + cr * 8];
            }
            #pragma unroll
            for (int mi = 0; mi < 4; mi++)
                #pragma unroll
                for (int n = 0; n < 4; n++) {
                    acc1[mi * 4 + n] = mfma16(af[mi], bq1[n], acc1[mi * 4 + n]);
                    acc2[mi * 4 + n] = mfma16(af[mi], bq2[n], acc2[mi * 4 + n]);
                }
        }
    };

    STAGE(0, 0);
    __syncthreads();
    int k0 = 0;
    #pragma unroll 1
    for (int it = 0; it < 7; ++it) {
        STAGE(1, k0 + 64);  COMPUTE(0); __syncthreads();
        STAGE(0, k0 + 128); COMPUTE(1); __syncthreads();
        k0 += 128;
    }
    STAGE(1, 960); COMPUTE(0); __syncthreads();
    COMPUTE(1);

    const int rq = (lane >> 4) * 4;
    const int cq = lane & 15;
    float bb1v[4], bb2v[4];
    #pragma unroll
    for (int ni = 0; ni < 4; ni++) {
        const int hcol = h0 + wc * 64 + ni * 16 + cq;
        bb1v[ni] = b1[e * HH + hcol] + b1a[e * HH + hcol];
        bb2v[ni] = b2[e * HH + hcol] + b2a[e * HH + hcol];
    }
    #pragma unroll
    for (int mi = 0; mi < 4; mi++) {
        #pragma unroll
        for (int ni = 0; ni < 4; ni++) {
            f32x4 v1 = acc1[mi * 4 + ni];
            f32x4 v2 = acc2[mi * 4 + ni];
            const int hcol = h0 + wc * 64 + ni * 16 + cq;
            #pragma unroll
            for (int r = 0; r < 4; r++) {
                const int pos = m0 + wr * 64 + mi * 16 + rq + r;
                if (pos < cnt) {
                    float x1 = v1[r] + bb1v[ni];
                    float x2 = v2[r] + bb2v[ni];
                    x2 = fminf(fmaxf(x2, -20.f), 20.f);
                    float hv = x1 * (x2 / (1.f + __expf(-x2)));
                    hv = fminf(fmaxf(hv, -1e4f), 1e4f);
                    hid[(size_t)(base + pos) * HH + hcol] = __float2bfloat16(hv);
                }
            }
        }
    }
}

// ---------------------------------------------------------------------------
// GEMM2: pairOut[pair,d] = gate * clip(hid@Wo + bo, +-1e4)
// BM=256, BN=128, BK=64, 8 waves, double-buffered 2-phase.
// ---------------------------------------------------------------------------
__global__ __launch_bounds__(512, 2) void gemm2_kernel(
    const __hip_bfloat16* __restrict__ hid, const __hip_bfloat16* __restrict__ wot,
    const float* __restrict__ bo, const int* __restrict__ counts,
    const float* __restrict__ gates_lin, float* __restrict__ pairOut)
{
    const int gid  = blockIdx.x;          // 0..1023
    const int xcd  = gid & 7;
    const int rest = gid >> 3;            // 0..127
    const int m    = rest & 15;
    const int pidx = rest >> 4;           // 0..7
    const int panel = xcd + 8 * pidx;     // 0..63
    const int e   = panel >> 3;
    const int d0  = (panel & 7) * 128;
    const int cnt = counts[e];
    const int m0  = m * 256;
    if (m0 >= cnt) return;
    int base = 0;
    #pragma unroll
    for (int j = 0; j < 8; j++) base += (j < e) ? counts[j] : 0;

    __shared__ __align__(16) __hip_bfloat16 As[2][256 * 64];
    __shared__ __align__(16) __hip_bfloat16 Bs[2][128 * 64];

    const int t = threadIdx.x;
    const int lane = t & 63;
    const int w = t >> 6;
    const int wr = w >> 1, wc = w & 1;
    const int rsel = lane & 15;

    f32x4 acc[16];
    const f32x4 z4 = {0.f, 0.f, 0.f, 0.f};
    #pragma unroll
    for (int q = 0; q < 16; q++) acc[q] = z4;

    const __hip_bfloat16* we = wot + ((size_t)e * DD + d0) * HH;

    const int l3 = lane >> 3;
    const int cs = (lane & 7) ^ l3;

    const __hip_bfloat16 *pA[4], *pB[2];
    #pragma unroll
    for (int i = 0; i < 4; i++) {
        const int row = i * 64 + w * 8 + l3;
        const int arow = base + min(m0 + row, cnt - 1);
        pA[i] = hid + (size_t)arow * HH + cs * 8;
    }
    #pragma unroll
    for (int i = 0; i < 2; i++) {
        const int row = i * 64 + w * 8 + l3;
        pB[i] = we + (size_t)row * HH + cs * 8;
    }

    auto STAGE = [&](int buf, int k0) {
        #pragma unroll
        for (int i = 0; i < 4; i++)
            __builtin_amdgcn_global_load_lds(AS1P(pA[i] + k0), AS3P(&As[buf][i * 4096 + w * 512]), 16, 0, 0);
        #pragma unroll
        for (int i = 0; i < 2; i++)
            __builtin_amdgcn_global_load_lds(AS1P(pB[i] + k0), AS3P(&Bs[buf][i * 4096 + w * 512]), 16, 0, 0);
    };
    auto COMPUTE = [&](int buf) {
        #pragma unroll
        for (int kk = 0; kk < 2; kk++) {
            const int gch = kk * 4 + (lane >> 4);
            bf16x8 af[4], bq[4];
            #pragma unroll
            for (int mi = 0; mi < 4; mi++) {
                const int row = wr * 64 + mi * 16 + rsel;
                af[mi] = *(const bf16x8*)&As[buf][row * 64 + (gch ^ (row & 7)) * 8];
            }
            #pragma unroll
            for (int n = 0; n < 4; n++) {
                const int row = wc * 64 + n * 16 + rsel;
                bq[n] = *(const bf16x8*)&Bs[buf][row * 64 + (gch ^ (row & 7)) * 8];
            }
            #pragma unroll
            for (int mi = 0; mi < 4; mi++)
                #pragma unroll
                for (int n = 0; n < 4; n++)
                    acc[mi * 4 + n] = mfma16(af[mi], bq[n], acc[mi * 4 + n]);
        }
    };

    STAGE(0, 0);
    __syncthreads();
    int k0 = 0;
    #pragma unroll 1
    for (int it = 0; it < 31; ++it) {
        STAGE(1, k0 + 64);  COMPUTE(0); __syncthreads();
        STAGE(0, k0 + 128); COMPUTE(1); __syncthreads();
        k0 += 128;
    }
    STAGE(1, 4032); COMPUTE(0); __syncthreads();
    COMPUTE(1);

    const int rq = (lane >> 4) * 4;
    const int cq = lane & 15;
    #pragma unroll
    for (int mi = 0; mi < 4; mi++) {
        #pragma unroll
        for (int ni = 0; ni < 4; ni++) {
            const int dcol = d0 + wc * 64 + ni * 16 + cq;
            const float bov = bo[e * DD + dcol];
            #pragma unroll
            for (int r = 0; r < 4; r++) {
                const int pos = m0 + wr * 64 + mi * 16 + rq + r;
                if (pos < cnt) {
                    const float gt = gates_lin[e * NN + pos];
                    float v = acc[mi * 4 + ni][r] + bov;
                    v = fminf(fmaxf(v, -1e4f), 1e4f);
                    pairOut[(size_t)(base + pos) * DD + dcol] = v * gt;
                }
            }
        }
    }
}

// ---------------------------------------------------------------------------
// Combine: out[token] = pairOut[slot0] + pairOut[slot1]
// ---------------------------------------------------------------------------
__global__ __launch_bounds__(256) void combine_kernel(
    const float* __restrict__ pairOut, const int* __restrict__ counts,
    const int* __restrict__ pairIdx, float* __restrict__ out)
{
    const int i = blockIdx.x;
    const int t = threadIdx.x;
    const int s0 = pairIdx[2 * i], s1 = pairIdx[2 * i + 1];
    const int e0 = s0 >> 12, p0 = s0 & (NN - 1);
    const int e1 = s1 >> 12, p1 = s1 & (NN - 1);
    int b0 = 0, b1 = 0;
    #pragma unroll
    for (int j = 0; j < 8; j++) {
        const int c = counts[j];
        b0 += (j < e0) ? c : 0;
        b1 += (j < e1) ? c : 0;
    }
    const float4 a = ((const float4*)(pairOut + (size_t)(b0 + p0) * DD))[t];
    const float4 b = ((const float4*)(pairOut + (size_t)(b1 + p1) * DD))[t];
    float4 r; r.x = a.x + b.x; r.y = a.y + b.y; r.z = a.z + b.z; r.w = a.w + b.w;
    ((float4*)(out + (size_t)i * DD))[t] = r;
}

// ---------------------------------------------------------------------------
extern "C" void kernel_launch(void* const* d_in, const int* in_sizes, int n_in,
                              void* d_out, int out_size, void* d_ws, size_t ws_size,
                              hipStream_t stream)
{
    const float* x   = (const float*)d_in[0];
    const float* lng = (const float*)d_in[1];
    const float* lnb = (const float*)d_in[2];
    const float* rw  = (const float*)d_in[3];
    const float* eg  = (const float*)d_in[4];
    const float* eb  = (const float*)d_in[5];
    const float* W1  = (const float*)d_in[6];
    const float* b1  = (const float*)d_in[7];
    const float* W2  = (const float*)d_in[8];
    const float* b2  = (const float*)d_in[9];
    const float* Wo  = (const float*)d_in[10];
    const float* bo  = (const float*)d_in[11];
    float* out = (float*)d_out;

    char* ws = (char*)d_ws;
    const size_t WSZ = (size_t)EE * HH * DD * 2;      // 64MB per weight matrix
    __hip_bfloat16* W1T  = (__hip_bfloat16*)(ws);
    __hip_bfloat16* W2T  = (__hip_bfloat16*)(ws + WSZ);
    __hip_bfloat16* WoT  = (__hip_bfloat16*)(ws + 2 * WSZ);
    __hip_bfloat16* xhat = (__hip_bfloat16*)(ws + 3 * WSZ);
    __hip_bfloat16* hid  = (__hip_bfloat16*)(ws + 3 * WSZ + (size_t)NN * DD * 2);
    char* small = ws + 3 * WSZ + (size_t)NN * DD * 2 + (size_t)2 * NN * HH * 2;
    int*   counts  = (int*)small;
    float* b1a     = (float*)(small + 256);
    float* b2a     = (float*)(small + 256 + 131072);
    int*   lists   = (int*)(small + 256 + 2 * 131072);
    float* gates   = (float*)(small + 256 + 3 * 131072);
    int*   pairIdx = (int*)(small + 256 + 4 * 131072);
    // pairOut (8192 x 1024 f32 = 32MB) aliases W1T (dead after gemm1; rewritten
    // by the transposes at the start of every call).
    float* pairOut = (float*)(ws);

    hipMemsetAsync(small, 0, 256 + 2 * 131072, stream);   // counts + b1a + b2a

    transpose_conv<true ><<<dim3(HH / 64, DD / 64, EE), 256, 0, stream>>>(W1, W1T, eg, eb, b1a, DD, HH);
    transpose_conv<true ><<<dim3(HH / 64, DD / 64, EE), 256, 0, stream>>>(W2, W2T, eg, eb, b2a, DD, HH);
    transpose_conv<false><<<dim3(DD / 64, HH / 64, EE), 256, 0, stream>>>(Wo, WoT, nullptr, nullptr, nullptr, HH, DD);

    token_kernel<<<NN, 256, 0, stream>>>(x, lng, lnb, rw, xhat, counts, lists, gates, pairIdx);

    gemm1_kernel<<<4096, 512, 0, stream>>>(
        xhat, W1T, W2T, b1, b2, b1a, b2a, counts, lists, hid);
    gemm2_kernel<<<1024, 512, 0, stream>>>(
        hid, WoT, bo, counts, gates, pairOut);
    combine_kernel<<<NN, 256, 0, stream>>>(pairOut, counts, pairIdx, out);
}

// Round 4
// 574.086 us; speedup vs baseline: 3.3078x; 1.0092x over previous
//
#include <hip/hip_runtime.h>
#include <hip/hip_bf16.h>

#define DD 1024
#define HH 4096
#define EE 8
#define NN 4096   // B*T tokens

typedef __attribute__((ext_vector_type(8))) short bf16x8;
typedef __attribute__((ext_vector_type(4))) float f32x4;
typedef __attribute__((ext_vector_type(8))) unsigned short u16x8;

#define AS1P(p) ((__attribute__((address_space(1))) void*)(unsigned long long)(const void*)(p))
#define AS3P(p) ((__attribute__((address_space(3))) void*)(unsigned int)(unsigned long long)(const void*)(p))

#define WAITV(N) asm volatile("s_waitcnt vmcnt(" #N ")" ::: "memory")

__device__ inline f32x4 mfma16(bf16x8 a, bf16x8 b, f32x4 c) {
    return __builtin_amdgcn_mfma_f32_16x16x32_bf16(a, b, c, 0, 0, 0);
}

// ---------------------------------------------------------------------------
// Transpose + fp32->bf16: dst[e][c][r] = src[e][r][c] * (SCALE? g[e][r] : 1)
// If SCALE: badd[e][c] += sum_r bvec[e][r]*src[e][r][c]   (eb @ W folded bias)
// ---------------------------------------------------------------------------
template <bool SCALE>
__global__ __launch_bounds__(256) void transpose_conv(
    const float* __restrict__ src, __hip_bfloat16* __restrict__ dst,
    const float* __restrict__ g, const float* __restrict__ bvec,
    float* __restrict__ badd, int R, int C)
{
    __shared__ float tile[64][65];
    __shared__ float sg[64], sb[64];
    const int e  = blockIdx.z;
    const int r0 = blockIdx.y * 64;
    const int c0 = blockIdx.x * 64;
    const int t  = threadIdx.x;
    const float* s = src + (size_t)e * R * C + (size_t)r0 * C + c0;

    if (SCALE && t < 64) {
        sg[t] = g[e * R + r0 + t];
        sb[t] = bvec[e * R + r0 + t];
    }
    #pragma unroll
    for (int i = 0; i < 4; i++) {
        const int rr = i * 16 + (t >> 4);
        const int cc = (t & 15) * 4;
        const float4 v = *(const float4*)(s + (size_t)rr * C + cc);
        tile[rr][cc] = v.x; tile[rr][cc + 1] = v.y;
        tile[rr][cc + 2] = v.z; tile[rr][cc + 3] = v.w;
    }
    __syncthreads();

    __hip_bfloat16* d = dst + (size_t)e * R * C + (size_t)c0 * R + r0;
    #pragma unroll
    for (int i = 0; i < 2; i++) {
        const int id = t + 256 * i;
        const int cc = id >> 3;          // dst-row (src col) 0..63
        const int rb = (id & 7) * 8;     // dst-col (src row) block
        union { u16x8 v; __hip_bfloat16 h[8]; } u;
        #pragma unroll
        for (int j = 0; j < 8; j++) {
            float v = tile[rb + j][cc];
            if (SCALE) v *= sg[rb + j];
            u.h[j] = __float2bfloat16(v);
        }
        *(u16x8*)(d + (size_t)cc * R + rb) = u.v;
    }
    if (SCALE && t < 64) {
        float sum = 0.f;
        #pragma unroll
        for (int rr = 0; rr < 64; rr++) sum += sb[rr] * tile[rr][t];
        atomicAdd(&badd[e * C + c0 + t], sum);
    }
}

// ---------------------------------------------------------------------------
// Per-token: LN1 -> router -> top2+softmax -> scatter; store LN2-normalized
// token (eg/eb folded into weights) as bf16; record (expert,slot) per token.
// ---------------------------------------------------------------------------
__global__ __launch_bounds__(256) void token_kernel(
    const float* __restrict__ x, const float* __restrict__ lng, const float* __restrict__ lnb,
    const float* __restrict__ rw, __hip_bfloat16* __restrict__ xhat,
    int* __restrict__ counts, int* __restrict__ lists, float* __restrict__ gates,
    int* __restrict__ pairIdx)
{
    const int i = blockIdx.x;
    const int t = threadIdx.x;
    __shared__ float sA[256], sB[256];
    __shared__ float slog[32];

    float4 xv = ((const float4*)(x + (size_t)i * DD))[t];
    float s1 = xv.x + xv.y + xv.z + xv.w;
    float s2 = xv.x * xv.x + xv.y * xv.y + xv.z * xv.z + xv.w * xv.w;
    sA[t] = s1; sB[t] = s2;
    __syncthreads();
    for (int s = 128; s > 0; s >>= 1) {
        if (t < s) { sA[t] += sA[t + s]; sB[t] += sB[t + s]; }
        __syncthreads();
    }
    const float mu  = sA[0] * (1.0f / DD);
    const float var = sB[0] * (1.0f / DD) - mu * mu;
    const float rstd = rsqrtf(var + 1e-5f);
    __syncthreads();

    float4 gv = ((const float4*)lng)[t];
    float4 bv = ((const float4*)lnb)[t];
    float xf[4];
    xf[0] = (xv.x - mu) * rstd * gv.x + bv.x;
    xf[1] = (xv.y - mu) * rstd * gv.y + bv.y;
    xf[2] = (xv.z - mu) * rstd * gv.z + bv.z;
    xf[3] = (xv.w - mu) * rstd * gv.w + bv.w;

    float lp[8];
    #pragma unroll
    for (int e = 0; e < 8; e++) lp[e] = 0.f;
    {
        const float4* r4 = (const float4*)(rw + (size_t)(t * 4) * EE);
        #pragma unroll
        for (int j = 0; j < 4; j++) {
            float4 ra = r4[j * 2], rb = r4[j * 2 + 1];
            lp[0] += xf[j] * ra.x; lp[1] += xf[j] * ra.y;
            lp[2] += xf[j] * ra.z; lp[3] += xf[j] * ra.w;
            lp[4] += xf[j] * rb.x; lp[5] += xf[j] * rb.y;
            lp[6] += xf[j] * rb.z; lp[7] += xf[j] * rb.w;
        }
    }
    const int lane = t & 63, wid = t >> 6;
    #pragma unroll
    for (int e = 0; e < 8; e++) {
        float v = lp[e];
        #pragma unroll
        for (int o = 32; o > 0; o >>= 1) v += __shfl_down(v, o, 64);
        if (lane == 0) slog[e * 4 + wid] = v;
    }

    s1 = xf[0] + xf[1] + xf[2] + xf[3];
    s2 = xf[0] * xf[0] + xf[1] * xf[1] + xf[2] * xf[2] + xf[3] * xf[3];
    sA[t] = s1; sB[t] = s2;
    __syncthreads();
    for (int s = 128; s > 0; s >>= 1) {
        if (t < s) { sA[t] += sA[t + s]; sB[t] += sB[t + s]; }
        __syncthreads();
    }
    const float mu2  = sA[0] * (1.0f / DD);
    const float var2 = sB[0] * (1.0f / DD) - mu2 * mu2;
    const float rstd2 = rsqrtf(var2 + 1e-5f);

    union { ushort4 v; __hip_bfloat16 h[4]; } u;
    u.h[0] = __float2bfloat16((xf[0] - mu2) * rstd2);
    u.h[1] = __float2bfloat16((xf[1] - mu2) * rstd2);
    u.h[2] = __float2bfloat16((xf[2] - mu2) * rstd2);
    u.h[3] = __float2bfloat16((xf[3] - mu2) * rstd2);
    ((ushort4*)(xhat + (size_t)i * DD))[t] = u.v;

    if (t == 0) {
        float lg[8];
        #pragma unroll
        for (int e = 0; e < 8; e++)
            lg[e] = slog[e * 4] + slog[e * 4 + 1] + slog[e * 4 + 2] + slog[e * 4 + 3];
        int i0 = 0;
        #pragma unroll
        for (int e = 1; e < 8; e++) if (lg[e] > lg[i0]) i0 = e;
        int i1 = (i0 == 0) ? 1 : 0;
        #pragma unroll
        for (int e = 0; e < 8; e++) { if (e != i0 && lg[e] > lg[i1]) i1 = e; }
        const float ex = __expf(lg[i1] - lg[i0]);   // <= 1
        const float g0 = 1.f / (1.f + ex);
        const float g1 = ex / (1.f + ex);
        int p0 = atomicAdd(&counts[i0], 1);
        lists[i0 * NN + p0] = i; gates[i0 * NN + p0] = g0;
        int p1 = atomicAdd(&counts[i1], 1);
        lists[i1 * NN + p1] = i; gates[i1 * NN + p1] = g1;
        pairIdx[2 * i]     = i0 * NN + p0;
        pairIdx[2 * i + 1] = i1 * NN + p1;
    }
}

// ---------------------------------------------------------------------------
// GEMM1: hid = clip( (A@W1'+b1') * silu(clip(A@W2'+b2', +-20)), +-1e4 )
// BM=256, BN=128(x2 matrices), BK=32 slices, 4-slice LDS ring, prefetch depth 3,
// counted vmcnt(8) + raw s_barrier (never drain to 0), setprio around MFMA.
// LDS layout: row pitch 64B, chunk-XOR swizzle c^( (row>>1)&3 ) applied as
// inverse on the global source (global_load_lds writes linearly) + on ds_read.
// ---------------------------------------------------------------------------
__global__ __launch_bounds__(512, 2) void gemm1_kernel(
    const __hip_bfloat16* __restrict__ xhat,
    const __hip_bfloat16* __restrict__ w1t, const __hip_bfloat16* __restrict__ w2t,
    const float* __restrict__ b1, const float* __restrict__ b2,
    const float* __restrict__ b1a, const float* __restrict__ b2a,
    const int* __restrict__ counts, const int* __restrict__ lists,
    __hip_bfloat16* __restrict__ hid)
{
    const int gid  = blockIdx.x;          // 0..4095
    const int xcd  = gid & 7;
    const int rest = gid >> 3;
    const int m    = rest & 15;
    const int pidx = rest >> 4;
    const int panel = xcd + 8 * pidx;     // all m-blocks of a panel on one XCD
    const int e   = panel >> 5;
    const int h0  = (panel & 31) * 128;
    const int cnt = counts[e];
    const int m0  = m * 256;
    if (m0 >= cnt) return;
    int base = 0;
    #pragma unroll
    for (int j = 0; j < 8; j++) base += (j < e) ? counts[j] : 0;

    __shared__ __align__(16) __hip_bfloat16 As [4][256 * 32];   // 64KB
    __shared__ __align__(16) __hip_bfloat16 B1s[4][128 * 32];   // 32KB
    __shared__ __align__(16) __hip_bfloat16 B2s[4][128 * 32];   // 32KB
    __shared__ int toks[256];

    const int t = threadIdx.x;
    const int lane = t & 63;
    const int w = t >> 6;                 // 0..7
    const int wr = w >> 1, wc = w & 1;    // 4x2 wave grid, each 64x64 per matrix
    const int rsel = lane & 15;
    const int crd  = lane >> 4;           // logical k-chunk 0..3
    const int cp   = crd ^ ((rsel >> 1) & 3);   // physical chunk for frag reads

    if (t < 256) toks[t] = lists[e * NN + min(m0 + t, cnt - 1)];

    f32x4 acc1[16], acc2[16];
    const f32x4 z4 = {0.f, 0.f, 0.f, 0.f};
    #pragma unroll
    for (int q = 0; q < 16; q++) { acc1[q] = z4; acc2[q] = z4; }

    const __hip_bfloat16* w1e = w1t + (size_t)e * HH * DD + (size_t)h0 * DD;
    const __hip_bfloat16* w2e = w2t + (size_t)e * HH * DD + (size_t)h0 * DD;

    __syncthreads();   // toks visible

    // staging sources: lane -> (row = base + lane>>2, phys chunk = lane&3)
    // global logical chunk = (lane&3) ^ ((row>>1)&3); row>>1 &3 is invariant
    // under +16, so one chunk-offset works for both A loads.
    const int rA = w * 32 + (lane >> 2);
    const int cA = (lane & 3) ^ ((rA >> 1) & 3);
    const __hip_bfloat16* pA0 = xhat + (size_t)toks[rA] * DD + cA * 8;
    const __hip_bfloat16* pA1 = xhat + (size_t)toks[rA + 16] * DD + cA * 8;
    const int rB = w * 16 + (lane >> 2);
    const int cB = (lane & 3) ^ ((rB >> 1) & 3);
    const __hip_bfloat16* pB1 = w1e + (size_t)rB * DD + cB * 8;
    const __hip_bfloat16* pB2 = w2e + (size_t)rB * DD + cB * 8;

    auto STAGE_A = [&](int buf, int s) {
        const int k0 = s * 32;
        __builtin_amdgcn_global_load_lds(AS1P(pA0 + k0), AS3P(&As[buf][w * 1024]), 16, 0, 0);
        __builtin_amdgcn_global_load_lds(AS1P(pA1 + k0), AS3P(&As[buf][w * 1024 + 512]), 16, 0, 0);
    };
    auto STAGE_B = [&](int buf, int s) {
        const int k0 = s * 32;
        __builtin_amdgcn_global_load_lds(AS1P(pB1 + k0), AS3P(&B1s[buf][w * 512]), 16, 0, 0);
        __builtin_amdgcn_global_load_lds(AS1P(pB2 + k0), AS3P(&B2s[buf][w * 512]), 16, 0, 0);
    };

    auto SLICE = [&](int buf, bool stage, int nbuf, int ns) {
        bf16x8 af[4], bq[4];
        #pragma unroll
        for (int mi = 0; mi < 4; mi++) {
            const int row = wr * 64 + mi * 16 + rsel;
            af[mi] = *(const bf16x8*)&As[buf][row * 32 + cp * 8];
        }
        #pragma unroll
        for (int n = 0; n < 4; n++) {
            const int row = wc * 64 + n * 16 + rsel;
            bq[n] = *(const bf16x8*)&B1s[buf][row * 32 + cp * 8];
        }
        if (stage) STAGE_A(nbuf, ns);
        __builtin_amdgcn_s_setprio(1);
        #pragma unroll
        for (int mi = 0; mi < 4; mi++)
            #pragma unroll
            for (int n = 0; n < 4; n++)
                acc1[mi * 4 + n] = mfma16(af[mi], bq[n], acc1[mi * 4 + n]);
        __builtin_amdgcn_s_setprio(0);
        #pragma unroll
        for (int n = 0; n < 4; n++) {
            const int row = wc * 64 + n * 16 + rsel;
            bq[n] = *(const bf16x8*)&B2s[buf][row * 32 + cp * 8];
        }
        if (stage) STAGE_B(nbuf, ns);
        __builtin_amdgcn_s_setprio(1);
        #pragma unroll
        for (int mi = 0; mi < 4; mi++)
            #pragma unroll
            for (int n = 0; n < 4; n++)
                acc2[mi * 4 + n] = mfma16(af[mi], bq[n], acc2[mi * 4 + n]);
        __builtin_amdgcn_s_setprio(0);
    };

    // prologue: 3 slices in flight (12 loads/wave)
    STAGE_A(0, 0); STAGE_B(0, 0);
    STAGE_A(1, 1); STAGE_B(1, 1);
    STAGE_A(2, 2); STAGE_B(2, 2);

    #pragma unroll 1
    for (int s = 0; s < 29; ++s) {
        WAITV(8);                          // slice s done; s+1,s+2 still flying
        __builtin_amdgcn_s_barrier();
        SLICE(s & 3, true, (s + 3) & 3, s + 3);
    }
    WAITV(8); __builtin_amdgcn_s_barrier(); SLICE(1, false, 0, 0);   // s=29
    WAITV(4); __builtin_amdgcn_s_barrier(); SLICE(2, false, 0, 0);   // s=30
    WAITV(0); __builtin_amdgcn_s_barrier(); SLICE(3, false, 0, 0);   // s=31

    const int rq = (lane >> 4) * 4;
    const int cq = lane & 15;
    float bb1v[4], bb2v[4];
    #pragma unroll
    for (int ni = 0; ni < 4; ni++) {
        const int hcol = h0 + wc * 64 + ni * 16 + cq;
        bb1v[ni] = b1[e * HH + hcol] + b1a[e * HH + hcol];
        bb2v[ni] = b2[e * HH + hcol] + b2a[e * HH + hcol];
    }
    #pragma unroll
    for (int mi = 0; mi < 4; mi++) {
        #pragma unroll
        for (int ni = 0; ni < 4; ni++) {
            f32x4 v1 = acc1[mi * 4 + ni];
            f32x4 v2 = acc2[mi * 4 + ni];
            const int hcol = h0 + wc * 64 + ni * 16 + cq;
            #pragma unroll
            for (int r = 0; r < 4; r++) {
                const int pos = m0 + wr * 64 + mi * 16 + rq + r;
                if (pos < cnt) {
                    float x1 = v1[r] + bb1v[ni];
                    float x2 = v2[r] + bb2v[ni];
                    x2 = fminf(fmaxf(x2, -20.f), 20.f);
                    float hv = x1 * (x2 / (1.f + __expf(-x2)));
                    hv = fminf(fmaxf(hv, -1e4f), 1e4f);
                    hid[(size_t)(base + pos) * HH + hcol] = __float2bfloat16(hv);
                }
            }
        }
    }
}

// ---------------------------------------------------------------------------
// GEMM2: pairOut[pair,d] = gate * clip(hid@Wo + bo, +-1e4)
// Same ring-pipeline structure; 128 slices of BK=32, vmcnt(6) (3 loads/slice).
// ---------------------------------------------------------------------------
__global__ __launch_bounds__(512, 2) void gemm2_kernel(
    const __hip_bfloat16* __restrict__ hid, const __hip_bfloat16* __restrict__ wot,
    const float* __restrict__ bo, const int* __restrict__ counts,
    const float* __restrict__ gates_lin, float* __restrict__ pairOut)
{
    const int gid  = blockIdx.x;          // 0..1023
    const int xcd  = gid & 7;
    const int rest = gid >> 3;
    const int m    = rest & 15;
    const int pidx = rest >> 4;
    const int panel = xcd + 8 * pidx;     // 0..63
    const int e   = panel >> 3;
    const int d0  = (panel & 7) * 128;
    const int cnt = counts[e];
    const int m0  = m * 256;
    if (m0 >= cnt) return;
    int base = 0;
    #pragma unroll
    for (int j = 0; j < 8; j++) base += (j < e) ? counts[j] : 0;

    __shared__ __align__(16) __hip_bfloat16 As[4][256 * 32];    // 64KB
    __shared__ __align__(16) __hip_bfloat16 Bs[4][128 * 32];    // 32KB

    const int t = threadIdx.x;
    const int lane = t & 63;
    const int w = t >> 6;
    const int wr = w >> 1, wc = w & 1;
    const int rsel = lane & 15;
    const int crd  = lane >> 4;
    const int cp   = crd ^ ((rsel >> 1) & 3);

    f32x4 acc[16];
    const f32x4 z4 = {0.f, 0.f, 0.f, 0.f};
    #pragma unroll
    for (int q = 0; q < 16; q++) acc[q] = z4;

    const __hip_bfloat16* we = wot + ((size_t)e * DD + d0) * HH;

    const int rA = w * 32 + (lane >> 2);
    const int cA = (lane & 3) ^ ((rA >> 1) & 3);
    const __hip_bfloat16* pA0 = hid + (size_t)(base + min(m0 + rA, cnt - 1)) * HH + cA * 8;
    const __hip_bfloat16* pA1 = hid + (size_t)(base + min(m0 + rA + 16, cnt - 1)) * HH + cA * 8;
    const int rB = w * 16 + (lane >> 2);
    const int cB = (lane & 3) ^ ((rB >> 1) & 3);
    const __hip_bfloat16* pB = we + (size_t)rB * HH + cB * 8;

    auto STAGE = [&](int buf, int s) {
        const int k0 = s * 32;
        __builtin_amdgcn_global_load_lds(AS1P(pA0 + k0), AS3P(&As[buf][w * 1024]), 16, 0, 0);
        __builtin_amdgcn_global_load_lds(AS1P(pA1 + k0), AS3P(&As[buf][w * 1024 + 512]), 16, 0, 0);
        __builtin_amdgcn_global_load_lds(AS1P(pB + k0), AS3P(&Bs[buf][w * 512]), 16, 0, 0);
    };

    auto SLICE = [&](int buf, bool stage, int nbuf, int ns) {
        bf16x8 af[4], bq[4];
        #pragma unroll
        for (int mi = 0; mi < 4; mi++) {
            const int row = wr * 64 + mi * 16 + rsel;
            af[mi] = *(const bf16x8*)&As[buf][row * 32 + cp * 8];
        }
        #pragma unroll
        for (int n = 0; n < 4; n++) {
            const int row = wc * 64 + n * 16 + rsel;
            bq[n] = *(const bf16x8*)&Bs[buf][row * 32 + cp * 8];
        }
        if (stage) STAGE(nbuf, ns);
        __builtin_amdgcn_s_setprio(1);
        #pragma unroll
        for (int mi = 0; mi < 4; mi++)
            #pragma unroll
            for (int n = 0; n < 4; n++)
                acc[mi * 4 + n] = mfma16(af[mi], bq[n], acc[mi * 4 + n]);
        __builtin_amdgcn_s_setprio(0);
    };

    STAGE(0, 0); STAGE(1, 1); STAGE(2, 2);

    #pragma unroll 1
    for (int s = 0; s < 125; ++s) {
        WAITV(6);
        __builtin_amdgcn_s_barrier();
        SLICE(s & 3, true, (s + 3) & 3, s + 3);
    }
    WAITV(6); __builtin_amdgcn_s_barrier(); SLICE(125 & 3, false, 0, 0);
    WAITV(3); __builtin_amdgcn_s_barrier(); SLICE(126 & 3, false, 0, 0);
    WAITV(0); __builtin_amdgcn_s_barrier(); SLICE(127 & 3, false, 0, 0);

    const int rq = (lane >> 4) * 4;
    const int cq = lane & 15;
    #pragma unroll
    for (int mi = 0; mi < 4; mi++) {
        #pragma unroll
        for (int ni = 0; ni < 4; ni++) {
            const int dcol = d0 + wc * 64 + ni * 16 + cq;
            const float bov = bo[e * DD + dcol];
            #pragma unroll
            for (int r = 0; r < 4; r++) {
                const int pos = m0 + wr * 64 + mi * 16 + rq + r;
                if (pos < cnt) {
                    const float gt = gates_lin[e * NN + pos];
                    float v = acc[mi * 4 + ni][r] + bov;
                    v = fminf(fmaxf(v, -1e4f), 1e4f);
                    pairOut[(size_t)(base + pos) * DD + dcol] = v * gt;
                }
            }
        }
    }
}

// ---------------------------------------------------------------------------
// Combine: out[token] = pairOut[slot0] + pairOut[slot1]
// ---------------------------------------------------------------------------
__global__ __launch_bounds__(256) void combine_kernel(
    const float* __restrict__ pairOut, const int* __restrict__ counts,
    const int* __restrict__ pairIdx, float* __restrict__ out)
{
    const int i = blockIdx.x;
    const int t = threadIdx.x;
    const int s0 = pairIdx[2 * i], s1 = pairIdx[2 * i + 1];
    const int e0 = s0 >> 12, p0 = s0 & (NN - 1);
    const int e1 = s1 >> 12, p1 = s1 & (NN - 1);
    int b0 = 0, b1 = 0;
    #pragma unroll
    for (int j = 0; j < 8; j++) {
        const int c = counts[j];
        b0 += (j < e0) ? c : 0;
        b1 += (j < e1) ? c : 0;
    }
    const float4 a = ((const float4*)(pairOut + (size_t)(b0 + p0) * DD))[t];
    const float4 b = ((const float4*)(pairOut + (size_t)(b1 + p1) * DD))[t];
    float4 r; r.x = a.x + b.x; r.y = a.y + b.y; r.z = a.z + b.z; r.w = a.w + b.w;
    ((float4*)(out + (size_t)i * DD))[t] = r;
}

// ---------------------------------------------------------------------------
extern "C" void kernel_launch(void* const* d_in, const int* in_sizes, int n_in,
                              void* d_out, int out_size, void* d_ws, size_t ws_size,
                              hipStream_t stream)
{
    const float* x   = (const float*)d_in[0];
    const float* lng = (const float*)d_in[1];
    const float* lnb = (const float*)d_in[2];
    const float* rw  = (const float*)d_in[3];
    const float* eg  = (const float*)d_in[4];
    const float* eb  = (const float*)d_in[5];
    const float* W1  = (const float*)d_in[6];
    const float* b1  = (const float*)d_in[7];
    const float* W2  = (const float*)d_in[8];
    const float* b2  = (const float*)d_in[9];
    const float* Wo  = (const float*)d_in[10];
    const float* bo  = (const float*)d_in[11];
    float* out = (float*)d_out;

    char* ws = (char*)d_ws;
    const size_t WSZ = (size_t)EE * HH * DD * 2;      // 64MB per weight matrix
    __hip_bfloat16* W1T  = (__hip_bfloat16*)(ws);
    __hip_bfloat16* W2T  = (__hip_bfloat16*)(ws + WSZ);
    __hip_bfloat16* WoT  = (__hip_bfloat16*)(ws + 2 * WSZ);
    __hip_bfloat16* xhat = (__hip_bfloat16*)(ws + 3 * WSZ);
    __hip_bfloat16* hid  = (__hip_bfloat16*)(ws + 3 * WSZ + (size_t)NN * DD * 2);
    char* small = ws + 3 * WSZ + (size_t)NN * DD * 2 + (size_t)2 * NN * HH * 2;
    int*   counts  = (int*)small;
    float* b1a     = (float*)(small + 256);
    float* b2a     = (float*)(small + 256 + 131072);
    int*   lists   = (int*)(small + 256 + 2 * 131072);
    float* gates   = (float*)(small + 256 + 3 * 131072);
    int*   pairIdx = (int*)(small + 256 + 4 * 131072);
    // pairOut (8192 x 1024 f32 = 32MB) aliases W1T (dead after gemm1; rewritten
    // by the transposes at the start of every call).
    float* pairOut = (float*)(ws);

    hipMemsetAsync(small, 0, 256 + 2 * 131072, stream);   // counts + b1a + b2a

    transpose_conv<true ><<<dim3(HH / 64, DD / 64, EE), 256, 0, stream>>>(W1, W1T, eg, eb, b1a, DD, HH);
    transpose_conv<true ><<<dim3(HH / 64, DD / 64, EE), 256, 0, stream>>>(W2, W2T, eg, eb, b2a, DD, HH);
    transpose_conv<false><<<dim3(DD / 64, HH / 64, EE), 256, 0, stream>>>(Wo, WoT, nullptr, nullptr, nullptr, HH, DD);

    token_kernel<<<NN, 256, 0, stream>>>(x, lng, lnb, rw, xhat, counts, lists, gates, pairIdx);

    gemm1_kernel<<<4096, 512, 0, stream>>>(
        xhat, W1T, W2T, b1, b2, b1a, b2a, counts, lists, hid);
    gemm2_kernel<<<1024, 512, 0, stream>>>(
        hid, WoT, bo, counts, gates, pairOut);
    combine_kernel<<<NN, 256, 0, stream>>>(pairOut, counts, pairIdx, out);
}

// Round 5
// 545.075 us; speedup vs baseline: 3.4839x; 1.0532x over previous
//
#include <hip/hip_runtime.h>
#include <hip/hip_bf16.h>

#define DD 1024
#define HH 4096
#define EE 8
#define NN 4096   // B*T tokens

typedef __attribute__((ext_vector_type(8))) short bf16x8;
typedef __attribute__((ext_vector_type(4))) float f32x4;
typedef __attribute__((ext_vector_type(8))) unsigned short u16x8;

#define AS1P(p) ((__attribute__((address_space(1))) void*)(unsigned long long)(const void*)(p))
#define AS3P(p) ((__attribute__((address_space(3))) void*)(unsigned int)(unsigned long long)(const void*)(p))

#define WAITV(N) asm volatile("s_waitcnt vmcnt(" #N ")" ::: "memory")
#define BARF     asm volatile("s_barrier" ::: "memory")
#define LGKM0    do { asm volatile("s_waitcnt lgkmcnt(0)" ::: "memory"); \
                      __builtin_amdgcn_sched_barrier(0); } while (0)

__device__ inline f32x4 mfma16(bf16x8 a, bf16x8 b, f32x4 c) {
    return __builtin_amdgcn_mfma_f32_16x16x32_bf16(a, b, c, 0, 0, 0);
}

// ---------------------------------------------------------------------------
// Transpose + fp32->bf16: dst[e][c][r] = src[e][r][c] * (SCALE? g[e][r] : 1)
// If SCALE: badd[e][c] += sum_r bvec[e][r]*src[e][r][c]
// ---------------------------------------------------------------------------
template <bool SCALE>
__global__ __launch_bounds__(256) void transpose_conv(
    const float* __restrict__ src, __hip_bfloat16* __restrict__ dst,
    const float* __restrict__ g, const float* __restrict__ bvec,
    float* __restrict__ badd, int R, int C)
{
    __shared__ float tile[64][65];
    __shared__ float sg[64], sb[64];
    const int e  = blockIdx.z;
    const int r0 = blockIdx.y * 64;
    const int c0 = blockIdx.x * 64;
    const int t  = threadIdx.x;
    const float* s = src + (size_t)e * R * C + (size_t)r0 * C + c0;

    if (SCALE && t < 64) {
        sg[t] = g[e * R + r0 + t];
        sb[t] = bvec[e * R + r0 + t];
    }
    #pragma unroll
    for (int i = 0; i < 4; i++) {
        const int rr = i * 16 + (t >> 4);
        const int cc = (t & 15) * 4;
        const float4 v = *(const float4*)(s + (size_t)rr * C + cc);
        tile[rr][cc] = v.x; tile[rr][cc + 1] = v.y;
        tile[rr][cc + 2] = v.z; tile[rr][cc + 3] = v.w;
    }
    __syncthreads();

    __hip_bfloat16* d = dst + (size_t)e * R * C + (size_t)c0 * R + r0;
    #pragma unroll
    for (int i = 0; i < 2; i++) {
        const int id = t + 256 * i;
        const int cc = id >> 3;
        const int rb = (id & 7) * 8;
        union { u16x8 v; __hip_bfloat16 h[8]; } u;
        #pragma unroll
        for (int j = 0; j < 8; j++) {
            float v = tile[rb + j][cc];
            if (SCALE) v *= sg[rb + j];
            u.h[j] = __float2bfloat16(v);
        }
        *(u16x8*)(d + (size_t)cc * R + rb) = u.v;
    }
    if (SCALE && t < 64) {
        float sum = 0.f;
        #pragma unroll
        for (int rr = 0; rr < 64; rr++) sum += sb[rr] * tile[rr][t];
        atomicAdd(&badd[e * C + c0 + t], sum);
    }
}

// ---------------------------------------------------------------------------
// Per-token: LN1 -> router -> top2+softmax -> scatter; store LN2-normalized
// token as bf16 (eg/eb folded into weights); record slots per token.
// ---------------------------------------------------------------------------
__global__ __launch_bounds__(256) void token_kernel(
    const float* __restrict__ x, const float* __restrict__ lng, const float* __restrict__ lnb,
    const float* __restrict__ rw, __hip_bfloat16* __restrict__ xhat,
    int* __restrict__ counts, int* __restrict__ lists, float* __restrict__ gates,
    int* __restrict__ pairIdx)
{
    const int i = blockIdx.x;
    const int t = threadIdx.x;
    __shared__ float sA[256], sB[256];
    __shared__ float slog[32];

    float4 xv = ((const float4*)(x + (size_t)i * DD))[t];
    float s1 = xv.x + xv.y + xv.z + xv.w;
    float s2 = xv.x * xv.x + xv.y * xv.y + xv.z * xv.z + xv.w * xv.w;
    sA[t] = s1; sB[t] = s2;
    __syncthreads();
    for (int s = 128; s > 0; s >>= 1) {
        if (t < s) { sA[t] += sA[t + s]; sB[t] += sB[t + s]; }
        __syncthreads();
    }
    const float mu  = sA[0] * (1.0f / DD);
    const float var = sB[0] * (1.0f / DD) - mu * mu;
    const float rstd = rsqrtf(var + 1e-5f);
    __syncthreads();

    float4 gv = ((const float4*)lng)[t];
    float4 bv = ((const float4*)lnb)[t];
    float xf[4];
    xf[0] = (xv.x - mu) * rstd * gv.x + bv.x;
    xf[1] = (xv.y - mu) * rstd * gv.y + bv.y;
    xf[2] = (xv.z - mu) * rstd * gv.z + bv.z;
    xf[3] = (xv.w - mu) * rstd * gv.w + bv.w;

    float lp[8];
    #pragma unroll
    for (int e = 0; e < 8; e++) lp[e] = 0.f;
    {
        const float4* r4 = (const float4*)(rw + (size_t)(t * 4) * EE);
        #pragma unroll
        for (int j = 0; j < 4; j++) {
            float4 ra = r4[j * 2], rb = r4[j * 2 + 1];
            lp[0] += xf[j] * ra.x; lp[1] += xf[j] * ra.y;
            lp[2] += xf[j] * ra.z; lp[3] += xf[j] * ra.w;
            lp[4] += xf[j] * rb.x; lp[5] += xf[j] * rb.y;
            lp[6] += xf[j] * rb.z; lp[7] += xf[j] * rb.w;
        }
    }
    const int lane = t & 63, wid = t >> 6;
    #pragma unroll
    for (int e = 0; e < 8; e++) {
        float v = lp[e];
        #pragma unroll
        for (int o = 32; o > 0; o >>= 1) v += __shfl_down(v, o, 64);
        if (lane == 0) slog[e * 4 + wid] = v;
    }

    s1 = xf[0] + xf[1] + xf[2] + xf[3];
    s2 = xf[0] * xf[0] + xf[1] * xf[1] + xf[2] * xf[2] + xf[3] * xf[3];
    sA[t] = s1; sB[t] = s2;
    __syncthreads();
    for (int s = 128; s > 0; s >>= 1) {
        if (t < s) { sA[t] += sA[t + s]; sB[t] += sB[t + s]; }
        __syncthreads();
    }
    const float mu2  = sA[0] * (1.0f / DD);
    const float var2 = sB[0] * (1.0f / DD) - mu2 * mu2;
    const float rstd2 = rsqrtf(var2 + 1e-5f);

    union { ushort4 v; __hip_bfloat16 h[4]; } u;
    u.h[0] = __float2bfloat16((xf[0] - mu2) * rstd2);
    u.h[1] = __float2bfloat16((xf[1] - mu2) * rstd2);
    u.h[2] = __float2bfloat16((xf[2] - mu2) * rstd2);
    u.h[3] = __float2bfloat16((xf[3] - mu2) * rstd2);
    ((ushort4*)(xhat + (size_t)i * DD))[t] = u.v;

    if (t == 0) {
        float lg[8];
        #pragma unroll
        for (int e = 0; e < 8; e++)
            lg[e] = slog[e * 4] + slog[e * 4 + 1] + slog[e * 4 + 2] + slog[e * 4 + 3];
        int i0 = 0;
        #pragma unroll
        for (int e = 1; e < 8; e++) if (lg[e] > lg[i0]) i0 = e;
        int i1 = (i0 == 0) ? 1 : 0;
        #pragma unroll
        for (int e = 0; e < 8; e++) { if (e != i0 && lg[e] > lg[i1]) i1 = e; }
        const float ex = __expf(lg[i1] - lg[i0]);
        const float g0 = 1.f / (1.f + ex);
        const float g1 = ex / (1.f + ex);
        int p0 = atomicAdd(&counts[i0], 1);
        lists[i0 * NN + p0] = i; gates[i0 * NN + p0] = g0;
        int p1 = atomicAdd(&counts[i1], 1);
        lists[i1 * NN + p1] = i; gates[i1 * NN + p1] = g1;
        pairIdx[2 * i]     = i0 * NN + p0;
        pairIdx[2 * i + 1] = i1 * NN + p1;
    }
}

// ---------------------------------------------------------------------------
// GEMM1 (8-phase): C[256 x 256] = A[256 x 1024] x B, B = W1/W2 interleaved at
// 16-col granularity (frag even=W1, odd=W2) so x1/x2 pair up lane-locally.
// 8 waves 2Mx4N, per-wave 128x64. LDS 128KB: As/Bs[2 dbuf][2 half][128*64].
// Per K-tile: 4 quadrant phases; stage-sets S1..S4 ordered by need; counted
// vmcnt (4,4,-,4); chunk-XOR swizzle phys = logical ^ (row&7) (conflict-free).
// ---------------------------------------------------------------------------
__global__ __launch_bounds__(512, 2) void gemm1_kernel(
    const __hip_bfloat16* __restrict__ xhat,
    const __hip_bfloat16* __restrict__ w1t, const __hip_bfloat16* __restrict__ w2t,
    const float* __restrict__ b1, const float* __restrict__ b2,
    const float* __restrict__ b1a, const float* __restrict__ b2a,
    const int* __restrict__ counts, const int* __restrict__ lists,
    __hip_bfloat16* __restrict__ hid)
{
    const int gid  = blockIdx.x;            // 0..4095
    const int xcd  = gid & 7;
    const int rest = gid >> 3;
    const int m    = rest & 15;
    const int pidx = rest >> 4;             // 0..31
    const int panel = xcd + 8 * pidx;       // 0..255: all m-blocks on one XCD
    const int e   = panel >> 5;
    const int h0  = (panel & 31) * 128;     // 128 h-cols per panel (x2 matrices)
    const int cnt = counts[e];
    const int m0  = m * 256;
    if (m0 >= cnt) return;
    int base = 0;
    #pragma unroll
    for (int j = 0; j < 8; j++) base += (j < e) ? counts[j] : 0;

    __shared__ __align__(16) __hip_bfloat16 As[2][2][128 * 64];   // 64KB
    __shared__ __align__(16) __hip_bfloat16 Bs[2][2][128 * 64];   // 64KB
    __shared__ int toks[256];

    const int t = threadIdx.x, lane = t & 63, w = t >> 6;
    const int wm = w >> 2, wn = w & 3;      // 2M x 4N waves, 128x64 each
    const int rsel = lane & 15, crd = lane >> 4;
    const int l3 = lane >> 3, cl = (lane & 7) ^ l3;   // inverse-swizzled src chunk

    if (t < 256) toks[t] = lists[e * NN + min(m0 + t, cnt - 1)];

    f32x4 acc[32];                          // [m 0..7][nl 0..3]
    const f32x4 z4 = {0.f, 0.f, 0.f, 0.f};
    #pragma unroll
    for (int q = 0; q < 32; q++) acc[q] = z4;

    const __hip_bfloat16* w1e = w1t + (size_t)e * HH * DD;
    const __hip_bfloat16* w2e = w2t + (size_t)e * HH * DD;
    __syncthreads();                        // toks visible

    // stage source pointers (row ≡ l3 mod 8 in every set => one cl works)
    const __hip_bfloat16 *paS1[2], *paS4[2], *pbS2[2];
    {
        const __hip_bfloat16* wsel = ((w >> 1) & 1) ? w2e : w1e;
        #pragma unroll
        for (int j = 0; j < 2; j++) {
            paS1[j] = xhat + (size_t)toks[j * 128 + w * 8 + l3] * DD + cl * 8;
            paS4[j] = xhat + (size_t)toks[j * 128 + 64 + w * 8 + l3] * DD + cl * 8;
            const int hc = h0 + (j * 4 + (w >> 2) * 2) * 16 + (w & 1) * 8 + l3;
            pbS2[j] = wsel + (size_t)hc * DD + cl * 8;
        }
    }

    auto S1 = [&](int b, int ko) {   // A rows 0:64, both halves
        __builtin_amdgcn_global_load_lds(AS1P(paS1[0] + ko), AS3P(&As[b][0][w * 512]), 16, 0, 0);
        __builtin_amdgcn_global_load_lds(AS1P(paS1[1] + ko), AS3P(&As[b][1][w * 512]), 16, 0, 0);
    };
    auto S2 = [&](int b, int ko) {   // B rows {0:32, 64:96} both halves (nq0 set)
        const int db = (w >> 2) * 4096 + (w & 3) * 512;
        __builtin_amdgcn_global_load_lds(AS1P(pbS2[0] + ko), AS3P(&Bs[b][0][db]), 16, 0, 0);
        __builtin_amdgcn_global_load_lds(AS1P(pbS2[1] + ko), AS3P(&Bs[b][1][db]), 16, 0, 0);
    };
    auto S3 = [&](int b, int ko) {   // B rows {32:64, 96:128} (nq1 set) = S2 + 16*DD
        const int db = (w >> 2) * 4096 + 2048 + (w & 3) * 512;
        __builtin_amdgcn_global_load_lds(AS1P(pbS2[0] + 16 * DD + ko), AS3P(&Bs[b][0][db]), 16, 0, 0);
        __builtin_amdgcn_global_load_lds(AS1P(pbS2[1] + 16 * DD + ko), AS3P(&Bs[b][1][db]), 16, 0, 0);
    };
    auto S4 = [&](int b, int ko) {   // A rows 64:128
        __builtin_amdgcn_global_load_lds(AS1P(paS4[0] + ko), AS3P(&As[b][0][4096 + w * 512]), 16, 0, 0);
        __builtin_amdgcn_global_load_lds(AS1P(paS4[1] + ko), AS3P(&As[b][1][4096 + w * 512]), 16, 0, 0);
    };

    bf16x8 af[4][2], bq[2][2];
    auto LDA = [&](int b, int mq) {
        #pragma unroll
        for (int mi2 = 0; mi2 < 4; mi2++)
            #pragma unroll
            for (int kk = 0; kk < 2; kk++) {
                const int r = mq * 64 + mi2 * 16 + rsel;
                const int k8 = kk * 4 + crd;
                af[mi2][kk] = *(const bf16x8*)&As[b][wm][r * 64 + ((k8 ^ (r & 7)) * 8)];
            }
    };
    auto LDB = [&](int b, int nq) {
        #pragma unroll
        for (int ni2 = 0; ni2 < 2; ni2++)
            #pragma unroll
            for (int kk = 0; kk < 2; kk++) {
                const int r = (wn & 1) * 64 + (nq * 2 + ni2) * 16 + rsel;
                const int k8 = kk * 4 + crd;
                bq[ni2][kk] = *(const bf16x8*)&Bs[b][wn >> 1][r * 64 + ((k8 ^ (r & 7)) * 8)];
            }
    };
    auto MQ = [&](int mq, int nq) {
        __builtin_amdgcn_s_setprio(1);
        #pragma unroll
        for (int mi2 = 0; mi2 < 4; mi2++)
            #pragma unroll
            for (int ni2 = 0; ni2 < 2; ni2++)
                #pragma unroll
                for (int kk = 0; kk < 2; kk++)
                    acc[(mq * 4 + mi2) * 4 + nq * 2 + ni2] =
                        mfma16(af[mi2][kk], bq[ni2][kk], acc[(mq * 4 + mi2) * 4 + nq * 2 + ni2]);
        __builtin_amdgcn_s_setprio(0);
    };

    // prologue: stage tile 0 in need-order
    S1(0, 0); S2(0, 0); S3(0, 0); S4(0, 0);
    WAITV(4); BARF;                         // S1,S2 landed; S3,S4 in flight

    #pragma unroll 1
    for (int tt = 0; tt < 15; ++tt) {
        const int cur = tt & 1, nxt = cur ^ 1;
        const int ko = (tt + 1) * 64;
        LDA(cur, 0); LDB(cur, 0); S1(nxt, ko);
        BARF; LGKM0; MQ(0, 0); WAITV(4); BARF;
        LDB(cur, 1); S2(nxt, ko);
        BARF; LGKM0; MQ(0, 1); WAITV(4); BARF;
        LDA(cur, 1); S3(nxt, ko);
        BARF; LGKM0; MQ(1, 1); BARF;
        LDB(cur, 0); S4(nxt, ko);
        BARF; LGKM0; MQ(1, 0); WAITV(4); BARF;
    }
    {   // epilogue tile 15 (cur = 1), no staging
        LDA(1, 0); LDB(1, 0); BARF; LGKM0; MQ(0, 0); WAITV(2); BARF;
        LDB(1, 1);            BARF; LGKM0; MQ(0, 1); WAITV(0); BARF;
        LDA(1, 1);            BARF; LGKM0; MQ(1, 1); BARF;
        LDB(1, 0);            BARF; LGKM0; MQ(1, 0);
    }

    // epilogue: x1 = acc[.][even], x2 = acc[.][odd] at the SAME (row, hcol)
    const int rq = (lane >> 4) * 4, cq = lane & 15;
    #pragma unroll
    for (int np = 0; np < 2; np++) {
        const int hcol = h0 + (wn * 2 + np) * 16 + cq;
        const float bb1 = b1[e * HH + hcol] + b1a[e * HH + hcol];
        const float bb2 = b2[e * HH + hcol] + b2a[e * HH + hcol];
        #pragma unroll
        for (int mi = 0; mi < 8; mi++) {
            f32x4 v1 = acc[mi * 4 + np * 2];
            f32x4 v2 = acc[mi * 4 + np * 2 + 1];
            #pragma unroll
            for (int r = 0; r < 4; r++) {
                const int pos = m0 + wm * 128 + mi * 16 + rq + r;
                if (pos < cnt) {
                    float x1 = v1[r] + bb1;
                    float x2 = v2[r] + bb2;
                    x2 = fminf(fmaxf(x2, -20.f), 20.f);
                    float hv = x1 * (x2 / (1.f + __expf(-x2)));
                    hv = fminf(fmaxf(hv, -1e4f), 1e4f);
                    hid[(size_t)(base + pos) * HH + hcol] = __float2bfloat16(hv);
                }
            }
        }
    }
}

// ---------------------------------------------------------------------------
// GEMM2 (8-phase, split-K=2): raw partial pairOut_sp[pair, d] = hid@Wo (K half)
// BM=256, BN=256, same phase machinery. bias/clip/gate applied in combine.
// ---------------------------------------------------------------------------
__global__ __launch_bounds__(512, 2) void gemm2_kernel(
    const __hip_bfloat16* __restrict__ hid, const __hip_bfloat16* __restrict__ wot,
    const int* __restrict__ counts, float* __restrict__ P0, float* __restrict__ P1)
{
    const int gid  = blockIdx.x;            // 0..1023
    const int xcd  = gid & 7;
    const int rest = gid >> 3;              // 0..127
    const int m    = rest & 15;
    const int sp   = (rest >> 4) & 1;
    const int pidx = rest >> 5;             // 0..3
    const int panel = xcd + 8 * pidx;       // 0..31
    const int e   = panel >> 2;
    const int d0  = (panel & 3) * 256;
    const int cnt = counts[e];
    const int m0  = m * 256;
    if (m0 >= cnt) return;
    int base = 0;
    #pragma unroll
    for (int j = 0; j < 8; j++) base += (j < e) ? counts[j] : 0;

    __shared__ __align__(16) __hip_bfloat16 As[2][2][128 * 64];
    __shared__ __align__(16) __hip_bfloat16 Bs[2][2][128 * 64];

    const int t = threadIdx.x, lane = t & 63, w = t >> 6;
    const int wm = w >> 2, wn = w & 3;
    const int rsel = lane & 15, crd = lane >> 4;
    const int l3 = lane >> 3, cl = (lane & 7) ^ l3;

    f32x4 acc[32];
    const f32x4 z4 = {0.f, 0.f, 0.f, 0.f};
    #pragma unroll
    for (int q = 0; q < 32; q++) acc[q] = z4;

    const int kbase = sp * 2048;            // this split's K range
    const __hip_bfloat16 *paS1[2], *paS4[2], *pbS2[2];
    #pragma unroll
    for (int j = 0; j < 2; j++) {
        paS1[j] = hid + (size_t)(base + min(m0 + j * 128 + w * 8 + l3, cnt - 1)) * HH + kbase + cl * 8;
        paS4[j] = hid + (size_t)(base + min(m0 + j * 128 + 64 + w * 8 + l3, cnt - 1)) * HH + kbase + cl * 8;
        const int dc = d0 + j * 128 + (w >> 2) * 64 + (w & 3) * 8 + l3;
        pbS2[j] = wot + ((size_t)e * DD + dc) * HH + kbase + cl * 8;
    }

    auto S1 = [&](int b, int ko) {
        __builtin_amdgcn_global_load_lds(AS1P(paS1[0] + ko), AS3P(&As[b][0][w * 512]), 16, 0, 0);
        __builtin_amdgcn_global_load_lds(AS1P(paS1[1] + ko), AS3P(&As[b][1][w * 512]), 16, 0, 0);
    };
    auto S2 = [&](int b, int ko) {
        const int db = (w >> 2) * 4096 + (w & 3) * 512;
        __builtin_amdgcn_global_load_lds(AS1P(pbS2[0] + ko), AS3P(&Bs[b][0][db]), 16, 0, 0);
        __builtin_amdgcn_global_load_lds(AS1P(pbS2[1] + ko), AS3P(&Bs[b][1][db]), 16, 0, 0);
    };
    auto S3 = [&](int b, int ko) {
        const int db = (w >> 2) * 4096 + 2048 + (w & 3) * 512;
        __builtin_amdgcn_global_load_lds(AS1P(pbS2[0] + 32 * HH + ko), AS3P(&Bs[b][0][db]), 16, 0, 0);
        __builtin_amdgcn_global_load_lds(AS1P(pbS2[1] + 32 * HH + ko), AS3P(&Bs[b][1][db]), 16, 0, 0);
    };
    auto S4 = [&](int b, int ko) {
        __builtin_amdgcn_global_load_lds(AS1P(paS4[0] + ko), AS3P(&As[b][0][4096 + w * 512]), 16, 0, 0);
        __builtin_amdgcn_global_load_lds(AS1P(paS4[1] + ko), AS3P(&As[b][1][4096 + w * 512]), 16, 0, 0);
    };

    bf16x8 af[4][2], bq[2][2];
    auto LDA = [&](int b, int mq) {
        #pragma unroll
        for (int mi2 = 0; mi2 < 4; mi2++)
            #pragma unroll
            for (int kk = 0; kk < 2; kk++) {
                const int r = mq * 64 + mi2 * 16 + rsel;
                const int k8 = kk * 4 + crd;
                af[mi2][kk] = *(const bf16x8*)&As[b][wm][r * 64 + ((k8 ^ (r & 7)) * 8)];
            }
    };
    auto LDB = [&](int b, int nq) {
        #pragma unroll
        for (int ni2 = 0; ni2 < 2; ni2++)
            #pragma unroll
            for (int kk = 0; kk < 2; kk++) {
                const int r = (wn & 1) * 64 + (nq * 2 + ni2) * 16 + rsel;
                const int k8 = kk * 4 + crd;
                bq[ni2][kk] = *(const bf16x8*)&Bs[b][wn >> 1][r * 64 + ((k8 ^ (r & 7)) * 8)];
            }
    };
    auto MQ = [&](int mq, int nq) {
        __builtin_amdgcn_s_setprio(1);
        #pragma unroll
        for (int mi2 = 0; mi2 < 4; mi2++)
            #pragma unroll
            for (int ni2 = 0; ni2 < 2; ni2++)
                #pragma unroll
                for (int kk = 0; kk < 2; kk++)
                    acc[(mq * 4 + mi2) * 4 + nq * 2 + ni2] =
                        mfma16(af[mi2][kk], bq[ni2][kk], acc[(mq * 4 + mi2) * 4 + nq * 2 + ni2]);
        __builtin_amdgcn_s_setprio(0);
    };

    S1(0, 0); S2(0, 0); S3(0, 0); S4(0, 0);
    WAITV(4); BARF;

    #pragma unroll 1
    for (int tt = 0; tt < 31; ++tt) {
        const int cur = tt & 1, nxt = cur ^ 1;
        const int ko = (tt + 1) * 64;
        LDA(cur, 0); LDB(cur, 0); S1(nxt, ko);
        BARF; LGKM0; MQ(0, 0); WAITV(4); BARF;
        LDB(cur, 1); S2(nxt, ko);
        BARF; LGKM0; MQ(0, 1); WAITV(4); BARF;
        LDA(cur, 1); S3(nxt, ko);
        BARF; LGKM0; MQ(1, 1); BARF;
        LDB(cur, 0); S4(nxt, ko);
        BARF; LGKM0; MQ(1, 0); WAITV(4); BARF;
    }
    {   // epilogue tile 31 (cur = 1)
        LDA(1, 0); LDB(1, 0); BARF; LGKM0; MQ(0, 0); WAITV(2); BARF;
        LDB(1, 1);            BARF; LGKM0; MQ(0, 1); WAITV(0); BARF;
        LDA(1, 1);            BARF; LGKM0; MQ(1, 1); BARF;
        LDB(1, 0);            BARF; LGKM0; MQ(1, 0);
    }

    float* dst = sp ? P1 : P0;
    const int rq = (lane >> 4) * 4, cq = lane & 15;
    #pragma unroll
    for (int nl = 0; nl < 4; nl++) {
        const int dcol = d0 + wn * 64 + nl * 16 + cq;
        #pragma unroll
        for (int mi = 0; mi < 8; mi++) {
            f32x4 v = acc[mi * 4 + nl];
            #pragma unroll
            for (int r = 0; r < 4; r++) {
                const int pos = m0 + wm * 128 + mi * 16 + rq + r;
                if (pos < cnt)
                    dst[(size_t)(base + pos) * DD + dcol] = v[r];
            }
        }
    }
}

// ---------------------------------------------------------------------------
// Combine: out[token] = sum_slots gate * clip(P0[slot]+P1[slot]+bo[e], +-1e4)
// ---------------------------------------------------------------------------
__global__ __launch_bounds__(256) void combine_kernel(
    const float* __restrict__ P0, const float* __restrict__ P1,
    const float* __restrict__ bo, const int* __restrict__ counts,
    const int* __restrict__ pairIdx, const float* __restrict__ gates,
    float* __restrict__ out)
{
    const int i = blockIdx.x;
    const int t = threadIdx.x;
    const int s0 = pairIdx[2 * i], s1 = pairIdx[2 * i + 1];
    const int e0 = s0 >> 12, p0 = s0 & (NN - 1);
    const int e1 = s1 >> 12, p1 = s1 & (NN - 1);
    int b0 = 0, b1 = 0;
    #pragma unroll
    for (int j = 0; j < 8; j++) {
        const int c = counts[j];
        b0 += (j < e0) ? c : 0;
        b1 += (j < e1) ? c : 0;
    }
    const float g0 = gates[s0], g1 = gates[s1];
    const size_t r0 = (size_t)(b0 + p0) * DD, r1 = (size_t)(b1 + p1) * DD;
    const float4 a0 = ((const float4*)(P0 + r0))[t], c0 = ((const float4*)(P1 + r0))[t];
    const float4 a1 = ((const float4*)(P0 + r1))[t], c1 = ((const float4*)(P1 + r1))[t];
    const float4 q0 = ((const float4*)(bo + (size_t)e0 * DD))[t];
    const float4 q1 = ((const float4*)(bo + (size_t)e1 * DD))[t];
    float4 r;
    #pragma unroll
    for (int k = 0; k < 4; k++) {
        float v0 = ((const float*)&a0)[k] + ((const float*)&c0)[k] + ((const float*)&q0)[k];
        float v1 = ((const float*)&a1)[k] + ((const float*)&c1)[k] + ((const float*)&q1)[k];
        v0 = fminf(fmaxf(v0, -1e4f), 1e4f);
        v1 = fminf(fmaxf(v1, -1e4f), 1e4f);
        ((float*)&r)[k] = g0 * v0 + g1 * v1;
    }
    ((float4*)(out + (size_t)i * DD))[t] = r;
}

// ---------------------------------------------------------------------------
extern "C" void kernel_launch(void* const* d_in, const int* in_sizes, int n_in,
                              void* d_out, int out_size, void* d_ws, size_t ws_size,
                              hipStream_t stream)
{
    const float* x   = (const float*)d_in[0];
    const float* lng = (const float*)d_in[1];
    const float* lnb = (const float*)d_in[2];
    const float* rw  = (const float*)d_in[3];
    const float* eg  = (const float*)d_in[4];
    const float* eb  = (const float*)d_in[5];
    const float* W1  = (const float*)d_in[6];
    const float* b1  = (const float*)d_in[7];
    const float* W2  = (const float*)d_in[8];
    const float* b2  = (const float*)d_in[9];
    const float* Wo  = (const float*)d_in[10];
    const float* bo  = (const float*)d_in[11];
    float* out = (float*)d_out;

    char* ws = (char*)d_ws;
    const size_t WSZ = (size_t)EE * HH * DD * 2;      // 64MB per weight matrix
    __hip_bfloat16* W1T  = (__hip_bfloat16*)(ws);
    __hip_bfloat16* W2T  = (__hip_bfloat16*)(ws + WSZ);
    __hip_bfloat16* WoT  = (__hip_bfloat16*)(ws + 2 * WSZ);
    __hip_bfloat16* xhat = (__hip_bfloat16*)(ws + 3 * WSZ);
    __hip_bfloat16* hid  = (__hip_bfloat16*)(ws + 3 * WSZ + (size_t)NN * DD * 2);
    char* small = ws + 3 * WSZ + (size_t)NN * DD * 2 + (size_t)2 * NN * HH * 2;
    int*   counts  = (int*)small;
    float* b1a     = (float*)(small + 256);
    float* b2a     = (float*)(small + 256 + 131072);
    int*   lists   = (int*)(small + 256 + 2 * 131072);
    float* gates   = (float*)(small + 256 + 3 * 131072);
    int*   pairIdx = (int*)(small + 256 + 4 * 131072);
    // split-K partials (each 8192 x 1024 f32 = 32MB) alias W1T / W2T, which are
    // dead after gemm1 and rewritten by the transposes at the start of each call.
    float* P0 = (float*)(ws);
    float* P1 = (float*)(ws + WSZ);

    hipMemsetAsync(small, 0, 256 + 2 * 131072, stream);   // counts + b1a + b2a

    transpose_conv<true ><<<dim3(HH / 64, DD / 64, EE), 256, 0, stream>>>(W1, W1T, eg, eb, b1a, DD, HH);
    transpose_conv<true ><<<dim3(HH / 64, DD / 64, EE), 256, 0, stream>>>(W2, W2T, eg, eb, b2a, DD, HH);
    transpose_conv<false><<<dim3(DD / 64, HH / 64, EE), 256, 0, stream>>>(Wo, WoT, nullptr, nullptr, nullptr, HH, DD);

    token_kernel<<<NN, 256, 0, stream>>>(x, lng, lnb, rw, xhat, counts, lists, gates, pairIdx);

    gemm1_kernel<<<4096, 512, 0, stream>>>(
        xhat, W1T, W2T, b1, b2, b1a, b2a, counts, lists, hid);
    gemm2_kernel<<<1024, 512, 0, stream>>>(
        hid, WoT, counts, P0, P1);
    combine_kernel<<<NN, 256, 0, stream>>>(P0, P1, bo, counts, pairIdx, gates, out);
}

// Round 6
// 539.635 us; speedup vs baseline: 3.5190x; 1.0101x over previous
//
#include <hip/hip_runtime.h>
#include <hip/hip_bf16.h>

#define DD 1024
#define HH 4096
#define EE 8
#define NN 4096   // B*T tokens

typedef __attribute__((ext_vector_type(8))) short bf16x8;
typedef __attribute__((ext_vector_type(4))) float f32x4;
typedef __attribute__((ext_vector_type(8))) unsigned short u16x8;

#define AS1P(p) ((__attribute__((address_space(1))) void*)(unsigned long long)(const void*)(p))
#define AS3P(p) ((__attribute__((address_space(3))) void*)(unsigned int)(unsigned long long)(const void*)(p))

__device__ inline f32x4 mfma16(bf16x8 a, bf16x8 b, f32x4 c) {
    return __builtin_amdgcn_mfma_f32_16x16x32_bf16(a, b, c, 0, 0, 0);
}

// ---------------------------------------------------------------------------
// Transpose + fp32->bf16: dst[e][c][r] = src[e][r][c] * (SCALE? g[e][r] : 1)
// If SCALE: badd[e][c] += sum_r bvec[e][r]*src[e][r][c]
// ---------------------------------------------------------------------------
template <bool SCALE>
__global__ __launch_bounds__(256) void transpose_conv(
    const float* __restrict__ src, __hip_bfloat16* __restrict__ dst,
    const float* __restrict__ g, const float* __restrict__ bvec,
    float* __restrict__ badd, int R, int C)
{
    __shared__ float tile[64][65];
    __shared__ float sg[64], sb[64];
    const int e  = blockIdx.z;
    const int r0 = blockIdx.y * 64;
    const int c0 = blockIdx.x * 64;
    const int t  = threadIdx.x;
    const float* s = src + (size_t)e * R * C + (size_t)r0 * C + c0;

    if (SCALE && t < 64) {
        sg[t] = g[e * R + r0 + t];
        sb[t] = bvec[e * R + r0 + t];
    }
    #pragma unroll
    for (int i = 0; i < 4; i++) {
        const int rr = i * 16 + (t >> 4);
        const int cc = (t & 15) * 4;
        const float4 v = *(const float4*)(s + (size_t)rr * C + cc);
        tile[rr][cc] = v.x; tile[rr][cc + 1] = v.y;
        tile[rr][cc + 2] = v.z; tile[rr][cc + 3] = v.w;
    }
    __syncthreads();

    __hip_bfloat16* d = dst + (size_t)e * R * C + (size_t)c0 * R + r0;
    #pragma unroll
    for (int i = 0; i < 2; i++) {
        const int id = t + 256 * i;
        const int cc = id >> 3;
        const int rb = (id & 7) * 8;
        union { u16x8 v; __hip_bfloat16 h[8]; } u;
        #pragma unroll
        for (int j = 0; j < 8; j++) {
            float v = tile[rb + j][cc];
            if (SCALE) v *= sg[rb + j];
            u.h[j] = __float2bfloat16(v);
        }
        *(u16x8*)(d + (size_t)cc * R + rb) = u.v;
    }
    if (SCALE && t < 64) {
        float sum = 0.f;
        #pragma unroll
        for (int rr = 0; rr < 64; rr++) sum += sb[rr] * tile[rr][t];
        atomicAdd(&badd[e * C + c0 + t], sum);
    }
}

// ---------------------------------------------------------------------------
// Per-token: LN1 -> router -> top2+softmax -> scatter; store LN2-normalized
// token as bf16 (eg/eb folded into weights); record slots per token.
// ---------------------------------------------------------------------------
__global__ __launch_bounds__(256) void token_kernel(
    const float* __restrict__ x, const float* __restrict__ lng, const float* __restrict__ lnb,
    const float* __restrict__ rw, __hip_bfloat16* __restrict__ xhat,
    int* __restrict__ counts, int* __restrict__ lists, float* __restrict__ gates,
    int* __restrict__ pairIdx)
{
    const int i = blockIdx.x;
    const int t = threadIdx.x;
    __shared__ float sA[256], sB[256];
    __shared__ float slog[32];

    float4 xv = ((const float4*)(x + (size_t)i * DD))[t];
    float s1 = xv.x + xv.y + xv.z + xv.w;
    float s2 = xv.x * xv.x + xv.y * xv.y + xv.z * xv.z + xv.w * xv.w;
    sA[t] = s1; sB[t] = s2;
    __syncthreads();
    for (int s = 128; s > 0; s >>= 1) {
        if (t < s) { sA[t] += sA[t + s]; sB[t] += sB[t + s]; }
        __syncthreads();
    }
    const float mu  = sA[0] * (1.0f / DD);
    const float var = sB[0] * (1.0f / DD) - mu * mu;
    const float rstd = rsqrtf(var + 1e-5f);
    __syncthreads();

    float4 gv = ((const float4*)lng)[t];
    float4 bv = ((const float4*)lnb)[t];
    float xf[4];
    xf[0] = (xv.x - mu) * rstd * gv.x + bv.x;
    xf[1] = (xv.y - mu) * rstd * gv.y + bv.y;
    xf[2] = (xv.z - mu) * rstd * gv.z + bv.z;
    xf[3] = (xv.w - mu) * rstd * gv.w + bv.w;

    float lp[8];
    #pragma unroll
    for (int e = 0; e < 8; e++) lp[e] = 0.f;
    {
        const float4* r4 = (const float4*)(rw + (size_t)(t * 4) * EE);
        #pragma unroll
        for (int j = 0; j < 4; j++) {
            float4 ra = r4[j * 2], rb = r4[j * 2 + 1];
            lp[0] += xf[j] * ra.x; lp[1] += xf[j] * ra.y;
            lp[2] += xf[j] * ra.z; lp[3] += xf[j] * ra.w;
            lp[4] += xf[j] * rb.x; lp[5] += xf[j] * rb.y;
            lp[6] += xf[j] * rb.z; lp[7] += xf[j] * rb.w;
        }
    }
    const int lane = t & 63, wid = t >> 6;
    #pragma unroll
    for (int e = 0; e < 8; e++) {
        float v = lp[e];
        #pragma unroll
        for (int o = 32; o > 0; o >>= 1) v += __shfl_down(v, o, 64);
        if (lane == 0) slog[e * 4 + wid] = v;
    }

    s1 = xf[0] + xf[1] + xf[2] + xf[3];
    s2 = xf[0] * xf[0] + xf[1] * xf[1] + xf[2] * xf[2] + xf[3] * xf[3];
    sA[t] = s1; sB[t] = s2;
    __syncthreads();
    for (int s = 128; s > 0; s >>= 1) {
        if (t < s) { sA[t] += sA[t + s]; sB[t] += sB[t + s]; }
        __syncthreads();
    }
    const float mu2  = sA[0] * (1.0f / DD);
    const float var2 = sB[0] * (1.0f / DD) - mu2 * mu2;
    const float rstd2 = rsqrtf(var2 + 1e-5f);

    union { ushort4 v; __hip_bfloat16 h[4]; } u;
    u.h[0] = __float2bfloat16((xf[0] - mu2) * rstd2);
    u.h[1] = __float2bfloat16((xf[1] - mu2) * rstd2);
    u.h[2] = __float2bfloat16((xf[2] - mu2) * rstd2);
    u.h[3] = __float2bfloat16((xf[3] - mu2) * rstd2);
    ((ushort4*)(xhat + (size_t)i * DD))[t] = u.v;

    if (t == 0) {
        float lg[8];
        #pragma unroll
        for (int e = 0; e < 8; e++)
            lg[e] = slog[e * 4] + slog[e * 4 + 1] + slog[e * 4 + 2] + slog[e * 4 + 3];
        int i0 = 0;
        #pragma unroll
        for (int e = 1; e < 8; e++) if (lg[e] > lg[i0]) i0 = e;
        int i1 = (i0 == 0) ? 1 : 0;
        #pragma unroll
        for (int e = 0; e < 8; e++) { if (e != i0 && lg[e] > lg[i1]) i1 = e; }
        const float ex = __expf(lg[i1] - lg[i0]);
        const float g0 = 1.f / (1.f + ex);
        const float g1 = ex / (1.f + ex);
        int p0 = atomicAdd(&counts[i0], 1);
        lists[i0 * NN + p0] = i; gates[i0 * NN + p0] = g0;
        int p1 = atomicAdd(&counts[i1], 1);
        lists[i1 * NN + p1] = i; gates[i1 * NN + p1] = g1;
        pairIdx[2 * i]     = i0 * NN + p0;
        pairIdx[2 * i + 1] = i1 * NN + p1;
    }
}

// ---------------------------------------------------------------------------
// GEMM1 v6: BM=128, BK=64, 64 h-cols (x W1,W2), 8 waves (2M x 4N), 64KB LDS
// -> 2 blocks/CU co-resident (the m97 overlap mechanism). Simple 2-phase dbuf.
// Swizzle: phys chunk = logical ^ (row&7); read offsets loop-invariant.
// ---------------------------------------------------------------------------
__global__ __launch_bounds__(512, 4) void gemm1_kernel(
    const __hip_bfloat16* __restrict__ xhat,
    const __hip_bfloat16* __restrict__ w1t, const __hip_bfloat16* __restrict__ w2t,
    const float* __restrict__ b1, const float* __restrict__ b2,
    const float* __restrict__ b1a, const float* __restrict__ b2a,
    const int* __restrict__ counts, const int* __restrict__ lists,
    __hip_bfloat16* __restrict__ hid)
{
    const int gid  = blockIdx.x;            // 0..8191
    const int xcd  = gid & 7;
    const int rest = gid >> 3;              // 0..1023
    const int m    = rest & 15;
    const int pidx = rest >> 4;             // 0..63
    const int panel = xcd + 8 * pidx;       // 0..511: all m-blocks of panel on one XCD
    const int e   = panel >> 6;
    const int h0  = (panel & 63) * 64;
    const int cnt = counts[e];
    const int m0  = m * 128;
    if (m0 >= cnt) return;
    int base = 0;
    #pragma unroll
    for (int j = 0; j < 8; j++) base += (j < e) ? counts[j] : 0;

    __shared__ __align__(16) __hip_bfloat16 As[2][128 * 64];   // 32KB
    __shared__ __align__(16) __hip_bfloat16 Bs[2][128 * 64];   // 32KB: rows 0-63 W1, 64-127 W2
    __shared__ int toks[128];

    const int t = threadIdx.x, lane = t & 63, w = t >> 6;
    const int wm = w >> 2, wn = w & 3;      // 2M x 4N; per-wave 64 rows x 16 cols x {W1,W2}
    const int rsel = lane & 15, crd = lane >> 4;
    const int rx = rsel & 7;
    const int l3 = lane >> 3, cs = (lane & 7) ^ l3;   // inverse-swizzled source chunk

    if (t < 128) toks[t] = lists[e * NN + min(m0 + t, cnt - 1)];

    f32x4 acc1[4], acc2[4];
    const f32x4 z4 = {0.f, 0.f, 0.f, 0.f};
    #pragma unroll
    for (int q = 0; q < 4; q++) { acc1[q] = z4; acc2[q] = z4; }

    __syncthreads();                        // toks visible

    const __hip_bfloat16* pA0 = xhat + (size_t)toks[w * 8 + l3] * DD + cs * 8;
    const __hip_bfloat16* pA1 = xhat + (size_t)toks[64 + w * 8 + l3] * DD + cs * 8;
    const __hip_bfloat16* pB1 = w1t + (size_t)e * HH * DD + (size_t)(h0 + w * 8 + l3) * DD + cs * 8;
    const __hip_bfloat16* pB2 = w2t + (size_t)e * HH * DD + (size_t)(h0 + w * 8 + l3) * DD + cs * 8;

    // loop-invariant read offsets (elements)
    int aoff[4];
    #pragma unroll
    for (int mi = 0; mi < 4; mi++) aoff[mi] = (wm * 64 + mi * 16 + rsel) * 64;
    const int boff1 = (wn * 16 + rsel) * 64;
    const int boff2 = boff1 + 64 * 64;
    const int koff0 = ((crd)     ^ rx) * 8;
    const int koff1 = ((4 + crd) ^ rx) * 8;

    auto STAGE = [&](int buf, int k0) {
        __builtin_amdgcn_global_load_lds(AS1P(pA0 + k0), AS3P(&As[buf][w * 512]), 16, 0, 0);
        __builtin_amdgcn_global_load_lds(AS1P(pA1 + k0), AS3P(&As[buf][4096 + w * 512]), 16, 0, 0);
        __builtin_amdgcn_global_load_lds(AS1P(pB1 + k0), AS3P(&Bs[buf][w * 512]), 16, 0, 0);
        __builtin_amdgcn_global_load_lds(AS1P(pB2 + k0), AS3P(&Bs[buf][4096 + w * 512]), 16, 0, 0);
    };
    auto COMPUTE = [&](int buf) {
        const __hip_bfloat16* A = As[buf];
        const __hip_bfloat16* B = Bs[buf];
        bf16x8 af[4][2], b1q[2], b2q[2];
        #pragma unroll
        for (int mi = 0; mi < 4; mi++) {
            af[mi][0] = *(const bf16x8*)&A[aoff[mi] + koff0];
            af[mi][1] = *(const bf16x8*)&A[aoff[mi] + koff1];
        }
        b1q[0] = *(const bf16x8*)&B[boff1 + koff0];
        b1q[1] = *(const bf16x8*)&B[boff1 + koff1];
        b2q[0] = *(const bf16x8*)&B[boff2 + koff0];
        b2q[1] = *(const bf16x8*)&B[boff2 + koff1];
        __builtin_amdgcn_s_setprio(1);
        #pragma unroll
        for (int mi = 0; mi < 4; mi++)
            #pragma unroll
            for (int kk = 0; kk < 2; kk++) {
                acc1[mi] = mfma16(af[mi][kk], b1q[kk], acc1[mi]);
                acc2[mi] = mfma16(af[mi][kk], b2q[kk], acc2[mi]);
            }
        __builtin_amdgcn_s_setprio(0);
    };

    STAGE(0, 0);
    __syncthreads();
    int k0 = 0;
    #pragma unroll 1
    for (int it = 0; it < 7; ++it) {
        STAGE(1, k0 + 64);  COMPUTE(0); __syncthreads();
        STAGE(0, k0 + 128); COMPUTE(1); __syncthreads();
        k0 += 128;
    }
    STAGE(1, 960); COMPUTE(0); __syncthreads();
    COMPUTE(1);

    const int rq = (lane >> 4) * 4, cq = lane & 15;
    const int hcol = h0 + wn * 16 + cq;
    const float bb1 = b1[e * HH + hcol] + b1a[e * HH + hcol];
    const float bb2 = b2[e * HH + hcol] + b2a[e * HH + hcol];
    #pragma unroll
    for (int mi = 0; mi < 4; mi++) {
        #pragma unroll
        for (int r = 0; r < 4; r++) {
            const int pos = m0 + wm * 64 + mi * 16 + rq + r;
            if (pos < cnt) {
                float x1 = acc1[mi][r] + bb1;
                float x2 = acc2[mi][r] + bb2;
                x2 = fminf(fmaxf(x2, -20.f), 20.f);
                float hv = x1 * (x2 / (1.f + __expf(-x2)));
                hv = fminf(fmaxf(hv, -1e4f), 1e4f);
                hid[(size_t)(base + pos) * HH + hcol] = __float2bfloat16(hv);
            }
        }
    }
}

// ---------------------------------------------------------------------------
// GEMM2 v6: BM=128, BN=128 d-cols, BK=64, split-K=2, 64KB LDS, 2 blocks/CU.
// Writes raw partials to P0/P1; bias/clip/gate in combine.
// ---------------------------------------------------------------------------
__global__ __launch_bounds__(512, 4) void gemm2_kernel(
    const __hip_bfloat16* __restrict__ hid, const __hip_bfloat16* __restrict__ wot,
    const int* __restrict__ counts, float* __restrict__ P0, float* __restrict__ P1)
{
    const int gid  = blockIdx.x;            // 0..2047
    const int xcd  = gid & 7;
    const int rest = gid >> 3;              // 0..255
    const int m    = rest & 15;
    const int sp   = (rest >> 4) & 1;
    const int pidx = rest >> 5;             // 0..7
    const int panel = xcd + 8 * pidx;       // 0..63
    const int e   = panel >> 3;
    const int d0  = (panel & 7) * 128;
    const int cnt = counts[e];
    const int m0  = m * 128;
    if (m0 >= cnt) return;
    int base = 0;
    #pragma unroll
    for (int j = 0; j < 8; j++) base += (j < e) ? counts[j] : 0;

    __shared__ __align__(16) __hip_bfloat16 As[2][128 * 64];   // 32KB
    __shared__ __align__(16) __hip_bfloat16 Bs[2][128 * 64];   // 32KB

    const int t = threadIdx.x, lane = t & 63, w = t >> 6;
    const int wm = w >> 2, wn = w & 3;      // per-wave 64 rows x 32 d-cols
    const int rsel = lane & 15, crd = lane >> 4;
    const int rx = rsel & 7;
    const int l3 = lane >> 3, cs = (lane & 7) ^ l3;

    f32x4 acc[4][2];
    const f32x4 z4 = {0.f, 0.f, 0.f, 0.f};
    #pragma unroll
    for (int q = 0; q < 4; q++) { acc[q][0] = z4; acc[q][1] = z4; }

    const size_t kbase = (size_t)sp * 2048;
    const __hip_bfloat16* pA0 = hid + (size_t)(base + min(m0 + w * 8 + l3, cnt - 1)) * HH + kbase + cs * 8;
    const __hip_bfloat16* pA1 = hid + (size_t)(base + min(m0 + 64 + w * 8 + l3, cnt - 1)) * HH + kbase + cs * 8;
    const __hip_bfloat16* pB0 = wot + ((size_t)e * DD + d0 + w * 8 + l3) * HH + kbase + cs * 8;
    const __hip_bfloat16* pB1 = wot + ((size_t)e * DD + d0 + 64 + w * 8 + l3) * HH + kbase + cs * 8;

    int aoff[4];
    #pragma unroll
    for (int mi = 0; mi < 4; mi++) aoff[mi] = (wm * 64 + mi * 16 + rsel) * 64;
    const int boffA = (wn * 32 + rsel) * 64;          // ni=0 frag row
    const int boffB = (wn * 32 + 16 + rsel) * 64;     // ni=1 frag row
    const int koff0 = ((crd)     ^ rx) * 8;
    const int koff1 = ((4 + crd) ^ rx) * 8;

    auto STAGE = [&](int buf, int k0) {
        __builtin_amdgcn_global_load_lds(AS1P(pA0 + k0), AS3P(&As[buf][w * 512]), 16, 0, 0);
        __builtin_amdgcn_global_load_lds(AS1P(pA1 + k0), AS3P(&As[buf][4096 + w * 512]), 16, 0, 0);
        __builtin_amdgcn_global_load_lds(AS1P(pB0 + k0), AS3P(&Bs[buf][w * 512]), 16, 0, 0);
        __builtin_amdgcn_global_load_lds(AS1P(pB1 + k0), AS3P(&Bs[buf][4096 + w * 512]), 16, 0, 0);
    };
    auto COMPUTE = [&](int buf) {
        const __hip_bfloat16* A = As[buf];
        const __hip_bfloat16* B = Bs[buf];
        bf16x8 af[4][2], bq[2][2];
        #pragma unroll
        for (int mi = 0; mi < 4; mi++) {
            af[mi][0] = *(const bf16x8*)&A[aoff[mi] + koff0];
            af[mi][1] = *(const bf16x8*)&A[aoff[mi] + koff1];
        }
        bq[0][0] = *(const bf16x8*)&B[boffA + koff0];
        bq[0][1] = *(const bf16x8*)&B[boffA + koff1];
        bq[1][0] = *(const bf16x8*)&B[boffB + koff0];
        bq[1][1] = *(const bf16x8*)&B[boffB + koff1];
        __builtin_amdgcn_s_setprio(1);
        #pragma unroll
        for (int mi = 0; mi < 4; mi++)
            #pragma unroll
            for (int kk = 0; kk < 2; kk++) {
                acc[mi][0] = mfma16(af[mi][kk], bq[0][kk], acc[mi][0]);
                acc[mi][1] = mfma16(af[mi][kk], bq[1][kk], acc[mi][1]);
            }
        __builtin_amdgcn_s_setprio(0);
    };

    STAGE(0, 0);
    __syncthreads();
    int k0 = 0;
    #pragma unroll 1
    for (int it = 0; it < 15; ++it) {
        STAGE(1, k0 + 64);  COMPUTE(0); __syncthreads();
        STAGE(0, k0 + 128); COMPUTE(1); __syncthreads();
        k0 += 128;
    }
    STAGE(1, 1984); COMPUTE(0); __syncthreads();
    COMPUTE(1);

    float* dst = sp ? P1 : P0;
    const int rq = (lane >> 4) * 4, cq = lane & 15;
    #pragma unroll
    for (int ni = 0; ni < 2; ni++) {
        const int dcol = d0 + wn * 32 + ni * 16 + cq;
        #pragma unroll
        for (int mi = 0; mi < 4; mi++) {
            f32x4 v = acc[mi][ni];
            #pragma unroll
            for (int r = 0; r < 4; r++) {
                const int pos = m0 + wm * 64 + mi * 16 + rq + r;
                if (pos < cnt)
                    dst[(size_t)(base + pos) * DD + dcol] = v[r];
            }
        }
    }
}

// ---------------------------------------------------------------------------
// Combine: out[token] = sum_slots gate * clip(P0[slot]+P1[slot]+bo[e], +-1e4)
// ---------------------------------------------------------------------------
__global__ __launch_bounds__(256) void combine_kernel(
    const float* __restrict__ P0, const float* __restrict__ P1,
    const float* __restrict__ bo, const int* __restrict__ counts,
    const int* __restrict__ pairIdx, const float* __restrict__ gates,
    float* __restrict__ out)
{
    const int i = blockIdx.x;
    const int t = threadIdx.x;
    const int s0 = pairIdx[2 * i], s1 = pairIdx[2 * i + 1];
    const int e0 = s0 >> 12, p0 = s0 & (NN - 1);
    const int e1 = s1 >> 12, p1 = s1 & (NN - 1);
    int b0 = 0, b1 = 0;
    #pragma unroll
    for (int j = 0; j < 8; j++) {
        const int c = counts[j];
        b0 += (j < e0) ? c : 0;
        b1 += (j < e1) ? c : 0;
    }
    const float g0 = gates[s0], g1 = gates[s1];
    const size_t r0 = (size_t)(b0 + p0) * DD, r1 = (size_t)(b1 + p1) * DD;
    const float4 a0 = ((const float4*)(P0 + r0))[t], c0 = ((const float4*)(P1 + r0))[t];
    const float4 a1 = ((const float4*)(P0 + r1))[t], c1 = ((const float4*)(P1 + r1))[t];
    const float4 q0 = ((const float4*)(bo + (size_t)e0 * DD))[t];
    const float4 q1 = ((const float4*)(bo + (size_t)e1 * DD))[t];
    float4 r;
    #pragma unroll
    for (int k = 0; k < 4; k++) {
        float v0 = ((const float*)&a0)[k] + ((const float*)&c0)[k] + ((const float*)&q0)[k];
        float v1 = ((const float*)&a1)[k] + ((const float*)&c1)[k] + ((const float*)&q1)[k];
        v0 = fminf(fmaxf(v0, -1e4f), 1e4f);
        v1 = fminf(fmaxf(v1, -1e4f), 1e4f);
        ((float*)&r)[k] = g0 * v0 + g1 * v1;
    }
    ((float4*)(out + (size_t)i * DD))[t] = r;
}

// ---------------------------------------------------------------------------
extern "C" void kernel_launch(void* const* d_in, const int* in_sizes, int n_in,
                              void* d_out, int out_size, void* d_ws, size_t ws_size,
                              hipStream_t stream)
{
    const float* x   = (const float*)d_in[0];
    const float* lng = (const float*)d_in[1];
    const float* lnb = (const float*)d_in[2];
    const float* rw  = (const float*)d_in[3];
    const float* eg  = (const float*)d_in[4];
    const float* eb  = (const float*)d_in[5];
    const float* W1  = (const float*)d_in[6];
    const float* b1  = (const float*)d_in[7];
    const float* W2  = (const float*)d_in[8];
    const float* b2  = (const float*)d_in[9];
    const float* Wo  = (const float*)d_in[10];
    const float* bo  = (const float*)d_in[11];
    float* out = (float*)d_out;

    char* ws = (char*)d_ws;
    const size_t WSZ = (size_t)EE * HH * DD * 2;      // 64MB per weight matrix
    __hip_bfloat16* W1T  = (__hip_bfloat16*)(ws);
    __hip_bfloat16* W2T  = (__hip_bfloat16*)(ws + WSZ);
    __hip_bfloat16* WoT  = (__hip_bfloat16*)(ws + 2 * WSZ);
    __hip_bfloat16* xhat = (__hip_bfloat16*)(ws + 3 * WSZ);
    __hip_bfloat16* hid  = (__hip_bfloat16*)(ws + 3 * WSZ + (size_t)NN * DD * 2);
    char* small = ws + 3 * WSZ + (size_t)NN * DD * 2 + (size_t)2 * NN * HH * 2;
    int*   counts  = (int*)small;
    float* b1a     = (float*)(small + 256);
    float* b2a     = (float*)(small + 256 + 131072);
    int*   lists   = (int*)(small + 256 + 2 * 131072);
    float* gates   = (float*)(small + 256 + 3 * 131072);
    int*   pairIdx = (int*)(small + 256 + 4 * 131072);
    // split-K partials (each 8192 x 1024 f32 = 32MB) alias W1T / W2T (dead after
    // gemm1; rewritten by the transposes at the start of every call).
    float* P0 = (float*)(ws);
    float* P1 = (float*)(ws + WSZ);

    hipMemsetAsync(small, 0, 256 + 2 * 131072, stream);   // counts + b1a + b2a

    transpose_conv<true ><<<dim3(HH / 64, DD / 64, EE), 256, 0, stream>>>(W1, W1T, eg, eb, b1a, DD, HH);
    transpose_conv<true ><<<dim3(HH / 64, DD / 64, EE), 256, 0, stream>>>(W2, W2T, eg, eb, b2a, DD, HH);
    transpose_conv<false><<<dim3(DD / 64, HH / 64, EE), 256, 0, stream>>>(Wo, WoT, nullptr, nullptr, nullptr, HH, DD);

    token_kernel<<<NN, 256, 0, stream>>>(x, lng, lnb, rw, xhat, counts, lists, gates, pairIdx);

    gemm1_kernel<<<8192, 512, 0, stream>>>(
        xhat, W1T, W2T, b1, b2, b1a, b2a, counts, lists, hid);
    gemm2_kernel<<<2048, 512, 0, stream>>>(
        hid, WoT, counts, P0, P1);
    combine_kernel<<<NN, 256, 0, stream>>>(P0, P1, bo, counts, pairIdx, gates, out);
}

// Round 7
// 538.979 us; speedup vs baseline: 3.5233x; 1.0012x over previous
//
#include <hip/hip_runtime.h>
#include <hip/hip_bf16.h>

#define DD 1024
#define HH 4096
#define EE 8
#define NN 4096   // B*T tokens

typedef __attribute__((ext_vector_type(8))) short bf16x8;
typedef __attribute__((ext_vector_type(4))) float f32x4;
typedef __attribute__((ext_vector_type(8))) unsigned short u16x8;

#define AS1P(p) ((__attribute__((address_space(1))) void*)(unsigned long long)(const void*)(p))
#define AS3P(p) ((__attribute__((address_space(3))) void*)(unsigned int)(unsigned long long)(const void*)(p))

__device__ inline f32x4 mfma16(bf16x8 a, bf16x8 b, f32x4 c) {
    return __builtin_amdgcn_mfma_f32_16x16x32_bf16(a, b, c, 0, 0, 0);
}

// ---------------------------------------------------------------------------
// Transpose + fp32->bf16: dst[e][c][r] = src[e][r][c] * (SCALE? g[e][r] : 1)
// If SCALE: badd[e][c] += sum_r bvec[e][r]*src[e][r][c]
// ---------------------------------------------------------------------------
template <bool SCALE>
__global__ __launch_bounds__(256) void transpose_conv(
    const float* __restrict__ src, __hip_bfloat16* __restrict__ dst,
    const float* __restrict__ g, const float* __restrict__ bvec,
    float* __restrict__ badd, int R, int C)
{
    __shared__ float tile[64][65];
    __shared__ float sg[64], sb[64];
    const int e  = blockIdx.z;
    const int r0 = blockIdx.y * 64;
    const int c0 = blockIdx.x * 64;
    const int t  = threadIdx.x;
    const float* s = src + (size_t)e * R * C + (size_t)r0 * C + c0;

    if (SCALE && t < 64) {
        sg[t] = g[e * R + r0 + t];
        sb[t] = bvec[e * R + r0 + t];
    }
    #pragma unroll
    for (int i = 0; i < 4; i++) {
        const int rr = i * 16 + (t >> 4);
        const int cc = (t & 15) * 4;
        const float4 v = *(const float4*)(s + (size_t)rr * C + cc);
        tile[rr][cc] = v.x; tile[rr][cc + 1] = v.y;
        tile[rr][cc + 2] = v.z; tile[rr][cc + 3] = v.w;
    }
    __syncthreads();

    __hip_bfloat16* d = dst + (size_t)e * R * C + (size_t)c0 * R + r0;
    #pragma unroll
    for (int i = 0; i < 2; i++) {
        const int id = t + 256 * i;
        const int cc = id >> 3;
        const int rb = (id & 7) * 8;
        union { u16x8 v; __hip_bfloat16 h[8]; } u;
        #pragma unroll
        for (int j = 0; j < 8; j++) {
            float v = tile[rb + j][cc];
            if (SCALE) v *= sg[rb + j];
            u.h[j] = __float2bfloat16(v);
        }
        *(u16x8*)(d + (size_t)cc * R + rb) = u.v;
    }
    if (SCALE && t < 64) {
        float sum = 0.f;
        #pragma unroll
        for (int rr = 0; rr < 64; rr++) sum += sb[rr] * tile[rr][t];
        atomicAdd(&badd[e * C + c0 + t], sum);
    }
}

// ---------------------------------------------------------------------------
// Per-token: LN1 -> router -> top2+softmax -> scatter; store LN2-normalized
// token as bf16 (eg/eb folded into weights); record slots per token.
// ---------------------------------------------------------------------------
__global__ __launch_bounds__(256) void token_kernel(
    const float* __restrict__ x, const float* __restrict__ lng, const float* __restrict__ lnb,
    const float* __restrict__ rw, __hip_bfloat16* __restrict__ xhat,
    int* __restrict__ counts, int* __restrict__ lists, float* __restrict__ gates,
    int* __restrict__ pairIdx)
{
    const int i = blockIdx.x;
    const int t = threadIdx.x;
    __shared__ float sA[256], sB[256];
    __shared__ float slog[32];

    float4 xv = ((const float4*)(x + (size_t)i * DD))[t];
    float s1 = xv.x + xv.y + xv.z + xv.w;
    float s2 = xv.x * xv.x + xv.y * xv.y + xv.z * xv.z + xv.w * xv.w;
    sA[t] = s1; sB[t] = s2;
    __syncthreads();
    for (int s = 128; s > 0; s >>= 1) {
        if (t < s) { sA[t] += sA[t + s]; sB[t] += sB[t + s]; }
        __syncthreads();
    }
    const float mu  = sA[0] * (1.0f / DD);
    const float var = sB[0] * (1.0f / DD) - mu * mu;
    const float rstd = rsqrtf(var + 1e-5f);
    __syncthreads();

    float4 gv = ((const float4*)lng)[t];
    float4 bv = ((const float4*)lnb)[t];
    float xf[4];
    xf[0] = (xv.x - mu) * rstd * gv.x + bv.x;
    xf[1] = (xv.y - mu) * rstd * gv.y + bv.y;
    xf[2] = (xv.z - mu) * rstd * gv.z + bv.z;
    xf[3] = (xv.w - mu) * rstd * gv.w + bv.w;

    float lp[8];
    #pragma unroll
    for (int e = 0; e < 8; e++) lp[e] = 0.f;
    {
        const float4* r4 = (const float4*)(rw + (size_t)(t * 4) * EE);
        #pragma unroll
        for (int j = 0; j < 4; j++) {
            float4 ra = r4[j * 2], rb = r4[j * 2 + 1];
            lp[0] += xf[j] * ra.x; lp[1] += xf[j] * ra.y;
            lp[2] += xf[j] * ra.z; lp[3] += xf[j] * ra.w;
            lp[4] += xf[j] * rb.x; lp[5] += xf[j] * rb.y;
            lp[6] += xf[j] * rb.z; lp[7] += xf[j] * rb.w;
        }
    }
    const int lane = t & 63, wid = t >> 6;
    #pragma unroll
    for (int e = 0; e < 8; e++) {
        float v = lp[e];
        #pragma unroll
        for (int o = 32; o > 0; o >>= 1) v += __shfl_down(v, o, 64);
        if (lane == 0) slog[e * 4 + wid] = v;
    }

    s1 = xf[0] + xf[1] + xf[2] + xf[3];
    s2 = xf[0] * xf[0] + xf[1] * xf[1] + xf[2] * xf[2] + xf[3] * xf[3];
    sA[t] = s1; sB[t] = s2;
    __syncthreads();
    for (int s = 128; s > 0; s >>= 1) {
        if (t < s) { sA[t] += sA[t + s]; sB[t] += sB[t + s]; }
        __syncthreads();
    }
    const float mu2  = sA[0] * (1.0f / DD);
    const float var2 = sB[0] * (1.0f / DD) - mu2 * mu2;
    const float rstd2 = rsqrtf(var2 + 1e-5f);

    union { ushort4 v; __hip_bfloat16 h[4]; } u;
    u.h[0] = __float2bfloat16((xf[0] - mu2) * rstd2);
    u.h[1] = __float2bfloat16((xf[1] - mu2) * rstd2);
    u.h[2] = __float2bfloat16((xf[2] - mu2) * rstd2);
    u.h[3] = __float2bfloat16((xf[3] - mu2) * rstd2);
    ((ushort4*)(xhat + (size_t)i * DD))[t] = u.v;

    if (t == 0) {
        float lg[8];
        #pragma unroll
        for (int e = 0; e < 8; e++)
            lg[e] = slog[e * 4] + slog[e * 4 + 1] + slog[e * 4 + 2] + slog[e * 4 + 3];
        int i0 = 0;
        #pragma unroll
        for (int e = 1; e < 8; e++) if (lg[e] > lg[i0]) i0 = e;
        int i1 = (i0 == 0) ? 1 : 0;
        #pragma unroll
        for (int e = 0; e < 8; e++) { if (e != i0 && lg[e] > lg[i1]) i1 = e; }
        const float ex = __expf(lg[i1] - lg[i0]);
        const float g0 = 1.f / (1.f + ex);
        const float g1 = ex / (1.f + ex);
        int p0 = atomicAdd(&counts[i0], 1);
        lists[i0 * NN + p0] = i; gates[i0 * NN + p0] = g0;
        int p1 = atomicAdd(&counts[i1], 1);
        lists[i1 * NN + p1] = i; gates[i1 * NN + p1] = g1;
        pairIdx[2 * i]     = i0 * NN + p0;
        pairIdx[2 * i + 1] = i1 * NN + p1;
    }
}

// ---------------------------------------------------------------------------
// GEMM1 v7: 4 waves (256 thr), BM=128, BK=32, 128 h-cols x {W1,W2}.
// Per-wave output = 128 rows x 32 W1-cols + 128 x 32 W2-cols (intensity 42.7
// FLOP/LDS-byte) AND 2 blocks/CU co-resident (48KB LDS, ~210 VGPR).
// Swizzle phys-chunk = logical ^ ((row>>1)&3): 2-way-free banks, verified 0
// conflicts in R4/R5. Simple 2-phase dbuf.
// ---------------------------------------------------------------------------
__global__ __launch_bounds__(256, 2) void gemm1_kernel(
    const __hip_bfloat16* __restrict__ xhat,
    const __hip_bfloat16* __restrict__ w1t, const __hip_bfloat16* __restrict__ w2t,
    const float* __restrict__ b1, const float* __restrict__ b2,
    const float* __restrict__ b1a, const float* __restrict__ b2a,
    const int* __restrict__ counts, const int* __restrict__ lists,
    __hip_bfloat16* __restrict__ hid)
{
    const int gid  = blockIdx.x;            // 0..4095
    const int xcd  = gid & 7;
    const int rest = gid >> 3;              // 0..511
    const int m    = rest & 15;
    const int pidx = rest >> 4;             // 0..31
    const int panel = xcd + 8 * pidx;       // 0..255: all m-blocks of panel on one XCD
    const int e   = panel >> 5;
    const int h0  = (panel & 31) * 128;
    const int cnt = counts[e];
    const int m0  = m * 128;
    if (m0 >= cnt) return;
    int base = 0;
    #pragma unroll
    for (int j = 0; j < 8; j++) base += (j < e) ? counts[j] : 0;

    __shared__ __align__(16) __hip_bfloat16 As[2][128 * 32];   // 8KB x2
    __shared__ __align__(16) __hip_bfloat16 Bs[2][256 * 32];   // 16KB x2: rows 0-127 W1, 128-255 W2
    __shared__ int toks[128];

    const int t = threadIdx.x, lane = t & 63, w = t >> 6;   // w = wn 0..3
    const int rsel = lane & 15, crd = lane >> 4;
    const int lr = lane >> 2;                               // staging row-in-16
    const int cl = (lane & 3) ^ ((lane >> 3) & 3);          // inverse-swizzled src chunk
    const int koff = (crd ^ ((rsel >> 1) & 3)) * 8;         // frag-read chunk (uniform)

    if (t < 128) toks[t] = lists[e * NN + min(m0 + t, cnt - 1)];

    f32x4 acc1[8][2], acc2[8][2];
    const f32x4 z4 = {0.f, 0.f, 0.f, 0.f};
    #pragma unroll
    for (int q = 0; q < 8; q++) {
        acc1[q][0] = z4; acc1[q][1] = z4;
        acc2[q][0] = z4; acc2[q][1] = z4;
    }

    __syncthreads();                        // toks visible

    const __hip_bfloat16* pA[2];
    #pragma unroll
    for (int i = 0; i < 2; i++)
        pA[i] = xhat + (size_t)toks[w * 32 + i * 16 + lr] * DD + cl * 8;
    const __hip_bfloat16* pB[4];
    {
        const __hip_bfloat16* wsel = (w < 2) ? w1t : w2t;
        #pragma unroll
        for (int i = 0; i < 4; i++) {
            const int brow = (w & 1) * 64 + i * 16 + lr;    // row within matrix
            pB[i] = wsel + ((size_t)e * HH + h0 + brow) * DD + cl * 8;
        }
    }

    auto STAGE = [&](int buf, int ko) {
        #pragma unroll
        for (int i = 0; i < 2; i++)
            __builtin_amdgcn_global_load_lds(AS1P(pA[i] + ko), AS3P(&As[buf][w * 1024 + i * 512 + lane * 8]), 16, 0, 0);
        #pragma unroll
        for (int i = 0; i < 4; i++)
            __builtin_amdgcn_global_load_lds(AS1P(pB[i] + ko), AS3P(&Bs[buf][w * 2048 + i * 512 + lane * 8]), 16, 0, 0);
    };
    auto COMPUTE = [&](int buf) {
        bf16x8 af[8], b1q[2], b2q[2];
        #pragma unroll
        for (int mi = 0; mi < 8; mi++)
            af[mi] = *(const bf16x8*)&As[buf][(mi * 16 + rsel) * 32 + koff];
        #pragma unroll
        for (int ni = 0; ni < 2; ni++) {
            b1q[ni] = *(const bf16x8*)&Bs[buf][(w * 32 + ni * 16 + rsel) * 32 + koff];
            b2q[ni] = *(const bf16x8*)&Bs[buf][(4096 + (w * 32 + ni * 16 + rsel) * 32) + koff];
        }
        __builtin_amdgcn_s_setprio(1);
        #pragma unroll
        for (int mi = 0; mi < 8; mi++)
            #pragma unroll
            for (int ni = 0; ni < 2; ni++) {
                acc1[mi][ni] = mfma16(af[mi], b1q[ni], acc1[mi][ni]);
                acc2[mi][ni] = mfma16(af[mi], b2q[ni], acc2[mi][ni]);
            }
        __builtin_amdgcn_s_setprio(0);
    };

    STAGE(0, 0);
    __syncthreads();
    int ko = 0;
    #pragma unroll 1
    for (int it = 0; it < 15; ++it) {
        STAGE(1, ko + 32); COMPUTE(0); __syncthreads();
        STAGE(0, ko + 64); COMPUTE(1); __syncthreads();
        ko += 64;
    }
    STAGE(1, 992); COMPUTE(0); __syncthreads();
    COMPUTE(1);

    const int rq = (lane >> 4) * 4, cq = lane & 15;
    #pragma unroll
    for (int ni = 0; ni < 2; ni++) {
        const int hcol = h0 + w * 32 + ni * 16 + cq;
        const float bb1 = b1[e * HH + hcol] + b1a[e * HH + hcol];
        const float bb2 = b2[e * HH + hcol] + b2a[e * HH + hcol];
        #pragma unroll
        for (int mi = 0; mi < 8; mi++) {
            f32x4 v1 = acc1[mi][ni];
            f32x4 v2 = acc2[mi][ni];
            #pragma unroll
            for (int r = 0; r < 4; r++) {
                const int pos = m0 + mi * 16 + rq + r;
                if (pos < cnt) {
                    float x1 = v1[r] + bb1;
                    float x2 = v2[r] + bb2;
                    x2 = fminf(fmaxf(x2, -20.f), 20.f);
                    float hv = x1 * (x2 / (1.f + __expf(-x2)));
                    hv = fminf(fmaxf(hv, -1e4f), 1e4f);
                    hid[(size_t)(base + pos) * HH + hcol] = __float2bfloat16(hv);
                }
            }
        }
    }
}

// ---------------------------------------------------------------------------
// GEMM2 v7: 4 waves, BM=128, BN=256 d-cols, BK=32, split-K=2; per-wave
// 128 x 64 output (32 accs). Raw partials to P0/P1; bias/clip/gate in combine.
// ---------------------------------------------------------------------------
__global__ __launch_bounds__(256, 2) void gemm2_kernel(
    const __hip_bfloat16* __restrict__ hid, const __hip_bfloat16* __restrict__ wot,
    const int* __restrict__ counts, float* __restrict__ P0, float* __restrict__ P1)
{
    const int gid  = blockIdx.x;            // 0..1023
    const int xcd  = gid & 7;
    const int rest = gid >> 3;              // 0..127
    const int m    = rest & 15;
    const int ps   = rest >> 4;             // 0..7
    const int panel = xcd + 8 * (ps >> 1);  // 0..31
    const int sp   = ps & 1;
    const int e   = panel >> 2;
    const int d0  = (panel & 3) * 256;
    const int cnt = counts[e];
    const int m0  = m * 128;
    if (m0 >= cnt) return;
    int base = 0;
    #pragma unroll
    for (int j = 0; j < 8; j++) base += (j < e) ? counts[j] : 0;

    __shared__ __align__(16) __hip_bfloat16 As[2][128 * 32];
    __shared__ __align__(16) __hip_bfloat16 Bs[2][256 * 32];

    const int t = threadIdx.x, lane = t & 63, w = t >> 6;
    const int rsel = lane & 15, crd = lane >> 4;
    const int lr = lane >> 2;
    const int cl = (lane & 3) ^ ((lane >> 3) & 3);
    const int koff = (crd ^ ((rsel >> 1) & 3)) * 8;

    f32x4 acc[8][4];
    const f32x4 z4 = {0.f, 0.f, 0.f, 0.f};
    #pragma unroll
    for (int q = 0; q < 8; q++) {
        acc[q][0] = z4; acc[q][1] = z4; acc[q][2] = z4; acc[q][3] = z4;
    }

    const int kbase = sp * 2048;
    const __hip_bfloat16* pA[2];
    #pragma unroll
    for (int i = 0; i < 2; i++)
        pA[i] = hid + (size_t)(base + min(m0 + w * 32 + i * 16 + lr, cnt - 1)) * HH + kbase + cl * 8;
    const __hip_bfloat16* pB[4];
    #pragma unroll
    for (int i = 0; i < 4; i++)
        pB[i] = wot + ((size_t)e * DD + d0 + w * 64 + i * 16 + lr) * HH + kbase + cl * 8;

    auto STAGE = [&](int buf, int ko) {
        #pragma unroll
        for (int i = 0; i < 2; i++)
            __builtin_amdgcn_global_load_lds(AS1P(pA[i] + ko), AS3P(&As[buf][w * 1024 + i * 512 + lane * 8]), 16, 0, 0);
        #pragma unroll
        for (int i = 0; i < 4; i++)
            __builtin_amdgcn_global_load_lds(AS1P(pB[i] + ko), AS3P(&Bs[buf][w * 2048 + i * 512 + lane * 8]), 16, 0, 0);
    };
    auto COMPUTE = [&](int buf) {
        bf16x8 af[8], bq[4];
        #pragma unroll
        for (int mi = 0; mi < 8; mi++)
            af[mi] = *(const bf16x8*)&As[buf][(mi * 16 + rsel) * 32 + koff];
        #pragma unroll
        for (int ni = 0; ni < 4; ni++)
            bq[ni] = *(const bf16x8*)&Bs[buf][(w * 64 + ni * 16 + rsel) * 32 + koff];
        __builtin_amdgcn_s_setprio(1);
        #pragma unroll
        for (int mi = 0; mi < 8; mi++)
            #pragma unroll
            for (int ni = 0; ni < 4; ni++)
                acc[mi][ni] = mfma16(af[mi], bq[ni], acc[mi][ni]);
        __builtin_amdgcn_s_setprio(0);
    };

    STAGE(0, 0);
    __syncthreads();
    int ko = 0;
    #pragma unroll 1
    for (int it = 0; it < 31; ++it) {
        STAGE(1, ko + 32); COMPUTE(0); __syncthreads();
        STAGE(0, ko + 64); COMPUTE(1); __syncthreads();
        ko += 64;
    }
    STAGE(1, 2016); COMPUTE(0); __syncthreads();
    COMPUTE(1);

    float* dst = sp ? P1 : P0;
    const int rq = (lane >> 4) * 4, cq = lane & 15;
    #pragma unroll
    for (int ni = 0; ni < 4; ni++) {
        const int dcol = d0 + w * 64 + ni * 16 + cq;
        #pragma unroll
        for (int mi = 0; mi < 8; mi++) {
            f32x4 v = acc[mi][ni];
            #pragma unroll
            for (int r = 0; r < 4; r++) {
                const int pos = m0 + mi * 16 + rq + r;
                if (pos < cnt)
                    dst[(size_t)(base + pos) * DD + dcol] = v[r];
            }
        }
    }
}

// ---------------------------------------------------------------------------
// Combine: out[token] = sum_slots gate * clip(P0[slot]+P1[slot]+bo[e], +-1e4)
// ---------------------------------------------------------------------------
__global__ __launch_bounds__(256) void combine_kernel(
    const float* __restrict__ P0, const float* __restrict__ P1,
    const float* __restrict__ bo, const int* __restrict__ counts,
    const int* __restrict__ pairIdx, const float* __restrict__ gates,
    float* __restrict__ out)
{
    const int i = blockIdx.x;
    const int t = threadIdx.x;
    const int s0 = pairIdx[2 * i], s1 = pairIdx[2 * i + 1];
    const int e0 = s0 >> 12, p0 = s0 & (NN - 1);
    const int e1 = s1 >> 12, p1 = s1 & (NN - 1);
    int b0 = 0, b1 = 0;
    #pragma unroll
    for (int j = 0; j < 8; j++) {
        const int c = counts[j];
        b0 += (j < e0) ? c : 0;
        b1 += (j < e1) ? c : 0;
    }
    const float g0 = gates[s0], g1 = gates[s1];
    const size_t r0 = (size_t)(b0 + p0) * DD, r1 = (size_t)(b1 + p1) * DD;
    const float4 a0 = ((const float4*)(P0 + r0))[t], c0 = ((const float4*)(P1 + r0))[t];
    const float4 a1 = ((const float4*)(P0 + r1))[t], c1 = ((const float4*)(P1 + r1))[t];
    const float4 q0 = ((const float4*)(bo + (size_t)e0 * DD))[t];
    const float4 q1 = ((const float4*)(bo + (size_t)e1 * DD))[t];
    float4 r;
    #pragma unroll
    for (int k = 0; k < 4; k++) {
        float v0 = ((const float*)&a0)[k] + ((const float*)&c0)[k] + ((const float*)&q0)[k];
        float v1 = ((const float*)&a1)[k] + ((const float*)&c1)[k] + ((const float*)&q1)[k];
        v0 = fminf(fmaxf(v0, -1e4f), 1e4f);
        v1 = fminf(fmaxf(v1, -1e4f), 1e4f);
        ((float*)&r)[k] = g0 * v0 + g1 * v1;
    }
    ((float4*)(out + (size_t)i * DD))[t] = r;
}

// ---------------------------------------------------------------------------
extern "C" void kernel_launch(void* const* d_in, const int* in_sizes, int n_in,
                              void* d_out, int out_size, void* d_ws, size_t ws_size,
                              hipStream_t stream)
{
    const float* x   = (const float*)d_in[0];
    const float* lng = (const float*)d_in[1];
    const float* lnb = (const float*)d_in[2];
    const float* rw  = (const float*)d_in[3];
    const float* eg  = (const float*)d_in[4];
    const float* eb  = (const float*)d_in[5];
    const float* W1  = (const float*)d_in[6];
    const float* b1  = (const float*)d_in[7];
    const float* W2  = (const float*)d_in[8];
    const float* b2  = (const float*)d_in[9];
    const float* Wo  = (const float*)d_in[10];
    const float* bo  = (const float*)d_in[11];
    float* out = (float*)d_out;

    char* ws = (char*)d_ws;
    const size_t WSZ = (size_t)EE * HH * DD * 2;      // 64MB per weight matrix
    __hip_bfloat16* W1T  = (__hip_bfloat16*)(ws);
    __hip_bfloat16* W2T  = (__hip_bfloat16*)(ws + WSZ);
    __hip_bfloat16* WoT  = (__hip_bfloat16*)(ws + 2 * WSZ);
    __hip_bfloat16* xhat = (__hip_bfloat16*)(ws + 3 * WSZ);
    __hip_bfloat16* hid  = (__hip_bfloat16*)(ws + 3 * WSZ + (size_t)NN * DD * 2);
    char* small = ws + 3 * WSZ + (size_t)NN * DD * 2 + (size_t)2 * NN * HH * 2;
    int*   counts  = (int*)small;
    float* b1a     = (float*)(small + 256);
    float* b2a     = (float*)(small + 256 + 131072);
    int*   lists   = (int*)(small + 256 + 2 * 131072);
    float* gates   = (float*)(small + 256 + 3 * 131072);
    int*   pairIdx = (int*)(small + 256 + 4 * 131072);
    // split-K partials (each 8192 x 1024 f32 = 32MB) alias W1T / W2T (dead after
    // gemm1; rewritten by the transposes at the start of every call).
    float* P0 = (float*)(ws);
    float* P1 = (float*)(ws + WSZ);

    hipMemsetAsync(small, 0, 256 + 2 * 131072, stream);   // counts + b1a + b2a

    transpose_conv<true ><<<dim3(HH / 64, DD / 64, EE), 256, 0, stream>>>(W1, W1T, eg, eb, b1a, DD, HH);
    transpose_conv<true ><<<dim3(HH / 64, DD / 64, EE), 256, 0, stream>>>(W2, W2T, eg, eb, b2a, DD, HH);
    transpose_conv<false><<<dim3(DD / 64, HH / 64, EE), 256, 0, stream>>>(Wo, WoT, nullptr, nullptr, nullptr, HH, DD);

    token_kernel<<<NN, 256, 0, stream>>>(x, lng, lnb, rw, xhat, counts, lists, gates, pairIdx);

    gemm1_kernel<<<4096, 256, 0, stream>>>(
        xhat, W1T, W2T, b1, b2, b1a, b2a, counts, lists, hid);
    gemm2_kernel<<<1024, 256, 0, stream>>>(
        hid, WoT, counts, P0, P1);
    combine_kernel<<<NN, 256, 0, stream>>>(P0, P1, bo, counts, pairIdx, gates, out);
}